// Round 14
// baseline (342.943 us; speedup 1.0000x reference)
//
#include <hip/hip_runtime.h>

#define DH 128
#define RMAXF 1.41421356237309515f
#define TGRID 2048

typedef float  floatx4 __attribute__((ext_vector_type(4)));
typedef float  floatx2 __attribute__((ext_vector_type(2)));
typedef short  shortx8 __attribute__((ext_vector_type(8)));
typedef int    intx4  __attribute__((ext_vector_type(4)));

__device__ __forceinline__ unsigned short f2bf(float f) {
    unsigned u = __builtin_bit_cast(unsigned, f);
    u += 0x7fffu + ((u >> 16) & 1u);
    return (unsigned short)(u >> 16);
}
__device__ __forceinline__ floatx2 unpack_bf2(unsigned u) {
    floatx2 r;
    r.x = __builtin_bit_cast(float, u << 16);
    r.y = __builtin_bit_cast(float, u & 0xffff0000u);
    return r;
}
__device__ __forceinline__ float fast_silu(float x) {
    return x * __builtin_amdgcn_rcpf(1.f + __expf(-x));
}

// ---- one prep kernel: bf16 transposed weights (W2P/cvec dots inline), bf16 NN RBF table,
//      cnt zero, PLUS node-encoder tail blocks ----
__global__ __launch_bounds__(256)
void prep_all_kernel(const float* __restrict__ pm_w1, const float* __restrict__ eh_w1,
                     const float* __restrict__ ph_w1, const float* __restrict__ ph_w2,
                     const float* __restrict__ pm_w2, const float* __restrict__ pm_b2,
                     unsigned short* __restrict__ W1abT, unsigned short* __restrict__ EHT,
                     unsigned short* __restrict__ PB1T, unsigned short* __restrict__ PH2T,
                     float* __restrict__ cvec, unsigned short* __restrict__ Tb,
                     int* __restrict__ cnt,
                     const float* __restrict__ xyr,
                     const float* __restrict__ nw1, const float* __restrict__ nb1,
                     const float* __restrict__ nw2, const float* __restrict__ nb2,
                     float* __restrict__ h, unsigned short* __restrict__ hbf,
                     int N, int PB) {
    if ((int)blockIdx.x >= PB) {
        __shared__ float xs[32][3];
        __shared__ float hid[32][DH];
        const int g = threadIdx.x >> 7;
        const int t = threadIdx.x & 127;
        const int n0 = ((int)blockIdx.x - PB) * 32 + g * 16;
        if (t < 48) {
            int i = t / 3, j = t - 3 * (t / 3);
            int n = n0 + i; if (n >= N) n = N - 1;
            xs[g * 16 + i][j] = xyr[3 * n + j];
        }
        __syncthreads();
        int col = t;
        float w10 = nw1[col], w11 = nw1[DH + col], w12 = nw1[2 * DH + col];
        float bb = nb1[col];
#pragma unroll
        for (int i = 0; i < 16; ++i) {
            float v = bb + xs[g * 16 + i][0] * w10 + xs[g * 16 + i][1] * w11 + xs[g * 16 + i][2] * w12;
            hid[g * 16 + i][col] = fast_silu(v);
        }
        __syncthreads();
        float a[16];
#pragma unroll
        for (int i = 0; i < 16; ++i) a[i] = nb2[col];
        for (int j = 0; j < DH; ++j) {
            float wv = nw2[j * DH + col];
#pragma unroll
            for (int i = 0; i < 16; ++i) a[i] += hid[g * 16 + i][j] * wv;
        }
        for (int i = 0; i < 16; ++i) {
            int n = n0 + i;
            if (n < N) {
                h[(size_t)n * DH + col] = a[i];
                hbf[(size_t)n * DH + col] = f2bf(a[i]);
            }
        }
        return;
    }
    int idx = blockIdx.x * 256 + threadIdx.x;
    const int nA = 3 * 256 * 128;
    const int nB = 256 * 128;
    const int nC = 3 * 128 * 256;
    const int nD = 3 * 128 * 128;
    const int nE = 3 * 128;
    const int nT = 3 * (TGRID + 1) * 128;
    if (idx < nA) {
        int l = idx / (256 * 128);
        int rem = idx - l * 256 * 128;
        int j = rem >> 7, k = rem & 127;
        int srow = ((j >> 7) << 7) + k;
        W1abT[idx] = f2bf(pm_w1[(size_t)l * 272 * 128 + (size_t)srow * 128 + (j & 127)]);
        return;
    }
    idx -= nA;
    if (idx < nB) {
        int j = idx >> 7, k = idx & 127;
        int srow = ((j >> 7) << 7) + k;
        EHT[idx] = f2bf(eh_w1[(size_t)srow * 128 + (j & 127)]);
        return;
    }
    idx -= nB;
    if (idx < nC) {
        int l = idx / (128 * 256);
        int rem = idx - l * 128 * 256;
        int j = rem >> 8, k = rem & 255;
        float v;
        if (k < 128) {
            v = ph_w1[(size_t)l * 256 * 128 + (size_t)k * 128 + j];
        } else {
            const float* w2r = pm_w2 + (size_t)l * 128 * 128 + (size_t)(k - 128) * 128;
            const float* p1b = ph_w1 + (size_t)l * 256 * 128 + (size_t)128 * 128 + j;
            float s = 0.f;
            for (int m = 0; m < 128; ++m) s += w2r[m] * p1b[(size_t)m * 128];
            v = s;
        }
        PB1T[idx] = f2bf(v);
        return;
    }
    idx -= nC;
    if (idx < nD) {
        int l = idx / (128 * 128);
        int rem = idx - l * 128 * 128;
        int j = rem >> 7, k = rem & 127;
        PH2T[idx] = f2bf(ph_w2[(size_t)l * 128 * 128 + (size_t)k * 128 + j]);
        return;
    }
    idx -= nD;
    if (idx < nE) {
        int l = idx >> 7, o = idx & 127;
        const float* b2 = pm_b2 + l * 128;
        const float* p1b = ph_w1 + (size_t)l * 256 * 128 + (size_t)128 * 128 + o;
        float s = 0.f;
        for (int m = 0; m < 128; ++m) s += b2[m] * p1b[(size_t)m * 128];
        cvec[idx] = s;
        return;
    }
    idx -= nE;
    if (idx < nT) {
        int l = idx / ((TGRID + 1) * 128);
        int rem = idx - l * (TGRID + 1) * 128;
        int i = rem >> 7, ch = rem & 127;
        float r = (float)i * (RMAXF / (float)TGRID);
        const float step = RMAXF / 15.f;
        const float gamma = 56.25f;
        const float* w1c = pm_w1 + (size_t)l * 272 * 128 + (size_t)256 * 128 + ch;
        float s = 0.f;
#pragma unroll
        for (int k = 0; k < 16; ++k) {
            float d = r - (float)k * step;
            s += expf(-gamma * d * d) * w1c[(size_t)k * 128];
        }
        Tb[idx] = f2bf(s);
        return;
    }
    idx -= nT;
    if (idx < N) cnt[idx] = 0;
}

// ---- CSR build ----
__global__ void count_kernel(const int* __restrict__ dst, int* __restrict__ cnt, int E) {
    int e = blockIdx.x * 256 + threadIdx.x;
    if (e < E) atomicAdd(&cnt[dst[e]], 1);
}
__global__ __launch_bounds__(1024)
void scan_kernel(const int* __restrict__ cnt, int* __restrict__ rs, int* __restrict__ cursor,
                 float* __restrict__ cntf, int N) {
    __shared__ int ps[1024];
    const int CH = 16;
    int t = threadIdx.x;
    int base = t * CH;
    int loc[CH];
    int s = 0;
#pragma unroll
    for (int j = 0; j < CH; ++j) {
        int i = base + j;
        int v = (i < N) ? cnt[i] : 0;
        if (i < N) cntf[i] = (float)v;
        loc[j] = s; s += v;
    }
    ps[t] = s;
    __syncthreads();
    for (int off = 1; off < 1024; off <<= 1) {
        int v = (t >= off) ? ps[t - off] : 0;
        __syncthreads();
        ps[t] += v;
        __syncthreads();
    }
    int pre = (t > 0) ? ps[t - 1] : 0;
#pragma unroll
    for (int j = 0; j < CH; ++j) {
        int i = base + j;
        if (i < N) { int v = pre + loc[j]; rs[i] = v; cursor[i] = v; }
    }
    if (t == 0) rs[N] = ps[1023];
}
// ---- fill: per CSR slot store packed {src | T-row-index<<18}; pads 32 tail slots ----
__global__ void fill_kernel(const int* __restrict__ src, const int* __restrict__ dst,
                            int* __restrict__ cursor, const float* __restrict__ xyr,
                            int* __restrict__ epack, int E) {
    int e = blockIdx.x * 256 + threadIdx.x;
    if (e < 32) epack[E + e] = 0;
    if (e >= E) return;
    int s = src[e], d = dst[e];
    int p = atomicAdd(&cursor[d], 1);
    float dx = xyr[3 * s] - xyr[3 * d];
    float dy = xyr[3 * s + 1] - xyr[3 * d + 1];
    float r = sqrtf(dx * dx + dy * dy + 1e-8f);
    int ti = (int)(r * ((float)TGRID / RMAXF) + 0.5f);
    ti = (ti > TGRID) ? TGRID : ti;
    epack[p] = s | (ti << 18);
}

// ---- proj (layer-0): Hsb||Hdb (bf16) = hbf @ W1abT^T ----
__global__ __launch_bounds__(256)
void proj_kernel(const unsigned short* __restrict__ Abf,
                 const unsigned short* __restrict__ BT,
                 unsigned short* __restrict__ O1b, unsigned short* __restrict__ O2b, int M) {
    const int tid = threadIdx.x;
    const int w = tid >> 6, lane = tid & 63;
    const int mr = lane & 15, q = lane >> 4;
    const int row0 = blockIdx.x * 64;
    floatx4 acc[4][4] = {};
#pragma unroll
    for (int kc = 0; kc < 4; ++kc) {
        const int ko = kc * 32 + q * 8;
        shortx8 a[4], b[4];
#pragma unroll
        for (int mt = 0; mt < 4; ++mt) {
            int r = row0 + mt * 16 + mr; if (r >= M) r = M - 1;
            a[mt] = *reinterpret_cast<const shortx8*>(Abf + (size_t)r * DH + ko);
        }
#pragma unroll
        for (int nt = 0; nt < 4; ++nt) {
            int ocol = w * 64 + nt * 16 + mr;
            b[nt] = *reinterpret_cast<const shortx8*>(BT + (size_t)ocol * DH + ko);
        }
#pragma unroll
        for (int mt = 0; mt < 4; ++mt)
#pragma unroll
            for (int nt = 0; nt < 4; ++nt)
                acc[mt][nt] = __builtin_amdgcn_mfma_f32_16x16x32_bf16(a[mt], b[nt], acc[mt][nt], 0, 0, 0);
    }
#pragma unroll
    for (int nt = 0; nt < 4; ++nt) {
        int ocol = w * 64 + nt * 16 + mr;
        unsigned short* O = (ocol < DH) ? O1b : O2b;
        int col = ocol & (DH - 1);
#pragma unroll
        for (int mt = 0; mt < 4; ++mt)
#pragma unroll
            for (int r4 = 0; r4 < 4; ++r4) {
                int gr = row0 + mt * 16 + q * 4 + r4;
                if (gr < M) O[(size_t)gr * DH + col] = f2bf(acc[mt][nt][r4]);
            }
    }
}

// ---- edge stream + aggregate: ONE WAVE = ONE NODE = ONE BLOCK; batch-8, 1-batch-deep prefetch ----
__global__ __launch_bounds__(64)
void edge_kernel(const unsigned short* __restrict__ Hsb, const unsigned short* __restrict__ Hdb,
                 const unsigned short* __restrict__ Tb,   // [TGRID+1][128] bf16 for this layer
                 const float* __restrict__ b1,
                 const int* __restrict__ rs, const int* __restrict__ epack,
                 unsigned int* __restrict__ Sbf, int N) {
    const int n = blockIdx.x;
    const int lane = threadIdx.x;
    const int c = lane * 2;
    floatx2 hdn = unpack_bf2(*(const unsigned*)(Hdb + (size_t)n * DH + c))
                + *(const floatx2*)(b1 + c);
    const int s = rs[n], e = rs[n + 1];
    floatx2 acc = {0.f, 0.f};
    const int cnt = e - s;
    if (cnt > 0) {
        const int nb = (cnt + 7) >> 3;
        intx4 pa = __builtin_nontemporal_load((const intx4*)(epack + s));
        intx4 pb = __builtin_nontemporal_load((const intx4*)(epack + s + 4));
        unsigned hu[8], tw[8];
        {
            int p[8] = {pa.x, pa.y, pa.z, pa.w, pb.x, pb.y, pb.z, pb.w};
#pragma unroll
            for (int i = 0; i < 8; ++i) {
                hu[i] = *(const unsigned*)(Hsb + (size_t)(p[i] & 0x3ffff) * DH + c);
                tw[i] = *(const unsigned*)(Tb + (size_t)(((unsigned)p[i]) >> 18) * DH + c);
            }
        }
        for (int b = 0; b < nb; ++b) {
            const int j = s + b * 8;
            intx4 paN = __builtin_nontemporal_load((const intx4*)(epack + j + 8));
            intx4 pbN = __builtin_nontemporal_load((const intx4*)(epack + j + 12));
            unsigned huN[8], twN[8];
            {
                int p[8] = {paN.x, paN.y, paN.z, paN.w, pbN.x, pbN.y, pbN.z, pbN.w};
#pragma unroll
                for (int i = 0; i < 8; ++i) {
                    huN[i] = *(const unsigned*)(Hsb + (size_t)(p[i] & 0x3ffff) * DH + c);
                    twN[i] = *(const unsigned*)(Tb + (size_t)(((unsigned)p[i]) >> 18) * DH + c);
                }
            }
#pragma unroll
            for (int i = 0; i < 8; ++i) {
                floatx2 pre = unpack_bf2(hu[i]) + hdn + unpack_bf2(tw[i]);
                floatx2 sg;
                sg.x = __builtin_amdgcn_rcpf(1.f + __expf(-pre.x));
                sg.y = __builtin_amdgcn_rcpf(1.f + __expf(-pre.y));
                float msk = (j + i < e) ? 1.f : 0.f;
                acc += (pre * sg) * msk;
            }
#pragma unroll
            for (int i = 0; i < 8; ++i) { hu[i] = huN[i]; tw[i] = twN[i]; }
        }
    }
    unsigned lo = f2bf(acc.x), hi = f2bf(acc.y);
    Sbf[(size_t)n * 64 + lane] = lo | (hi << 16);
}

// ---- node update + fused next-layer projection; 64-row tiles ----
template<int LAST>
__global__ __launch_bounds__(256)
void upd_kernel(unsigned short* hbf,
                const unsigned short* __restrict__ Sbf16,
                float* h,
                const unsigned short* __restrict__ PB1T,   // [128][256]
                const float* __restrict__ b1v,
                const float* __restrict__ cvec,            // [128]
                const float* __restrict__ cntf,
                const unsigned short* __restrict__ P2T,    // [128][128]
                const float* __restrict__ b2v,
                const float* __restrict__ g, const float* __restrict__ bb,
                const unsigned short* __restrict__ BT,     // [256][128] next-proj
                unsigned short* __restrict__ O1b, unsigned short* __restrict__ O2b,  // LAST=0
                float* __restrict__ O1f, float* __restrict__ O2f,                    // LAST=1
                int M) {
    __shared__ unsigned short HID[64 * 136];
    __shared__ float red[4][64][2];
    __shared__ float stats[64][2];
    __shared__ float cntL[64];
    const int tid = threadIdx.x;
    const int w = tid >> 6, lane = tid & 63;
    const int mr = lane & 15, q = lane >> 4;
    const int row0 = blockIdx.x * 64;

    if (tid < 64) {
        int r = row0 + tid;
        cntL[tid] = (r < M) ? cntf[r] : 0.f;
    }
    __syncthreads();

    floatx4 acc[4][2] = {};
#pragma unroll
    for (int kc = 0; kc < 8; ++kc) {
        const int ko = kc * 32 + q * 8;
        shortx8 a[4], bfr[2];
#pragma unroll
        for (int mt = 0; mt < 4; ++mt) {
            int r = row0 + mt * 16 + mr; if (r >= M) r = M - 1;
            const unsigned short* sp = (ko < DH) ? (hbf + (size_t)r * DH + ko)
                                                 : (Sbf16 + (size_t)r * DH + (ko - DH));
            a[mt] = *reinterpret_cast<const shortx8*>(sp);
        }
#pragma unroll
        for (int nt = 0; nt < 2; ++nt)
            bfr[nt] = *reinterpret_cast<const shortx8*>(PB1T + (size_t)(w * 32 + nt * 16 + mr) * 256 + ko);
#pragma unroll
        for (int mt = 0; mt < 4; ++mt)
#pragma unroll
            for (int nt = 0; nt < 2; ++nt)
                acc[mt][nt] = __builtin_amdgcn_mfma_f32_16x16x32_bf16(a[mt], bfr[nt], acc[mt][nt], 0, 0, 0);
    }
#pragma unroll
    for (int nt = 0; nt < 2; ++nt) {
        int col = w * 32 + nt * 16 + mr;
        float bv = b1v[col], cv = cvec[col];
#pragma unroll
        for (int mt = 0; mt < 4; ++mt)
#pragma unroll
            for (int r4 = 0; r4 < 4; ++r4) {
                int row = mt * 16 + q * 4 + r4;
                HID[row * 136 + col] = f2bf(fast_silu(acc[mt][nt][r4] + bv + cntL[row] * cv));
            }
    }
    __syncthreads();

    floatx4 acc3[4][2] = {};
#pragma unroll
    for (int kc = 0; kc < 4; ++kc) {
        const int ko = kc * 32 + q * 8;
        shortx8 a[4], bfr[2];
#pragma unroll
        for (int mt = 0; mt < 4; ++mt)
            a[mt] = *reinterpret_cast<const shortx8*>(HID + (mt * 16 + mr) * 136 + ko);
#pragma unroll
        for (int nt = 0; nt < 2; ++nt)
            bfr[nt] = *reinterpret_cast<const shortx8*>(P2T + (size_t)(w * 32 + nt * 16 + mr) * DH + ko);
#pragma unroll
        for (int mt = 0; mt < 4; ++mt)
#pragma unroll
            for (int nt = 0; nt < 2; ++nt)
                acc3[mt][nt] = __builtin_amdgcn_mfma_f32_16x16x32_bf16(a[mt], bfr[nt], acc3[mt][nt], 0, 0, 0);
    }
#pragma unroll
    for (int nt = 0; nt < 2; ++nt) {
        int col = w * 32 + nt * 16 + mr;
        float b2c = b2v[col];
#pragma unroll
        for (int mt = 0; mt < 4; ++mt)
#pragma unroll
            for (int r4 = 0; r4 < 4; ++r4) {
                int gr = row0 + mt * 16 + q * 4 + r4;
                float hv = (gr < M) ? h[(size_t)gr * DH + col] : 0.f;
                acc3[mt][nt][r4] = acc3[mt][nt][r4] + b2c + hv;
            }
    }
#pragma unroll
    for (int mt = 0; mt < 4; ++mt)
#pragma unroll
        for (int r4 = 0; r4 < 4; ++r4) {
            float y0 = acc3[mt][0][r4], y1 = acc3[mt][1][r4];
            float s1 = y0 + y1, s2 = y0 * y0 + y1 * y1;
#pragma unroll
            for (int m = 1; m < 16; m <<= 1) {
                s1 += __shfl_xor(s1, m);
                s2 += __shfl_xor(s2, m);
            }
            if (mr == 0) {
                int row = mt * 16 + q * 4 + r4;
                red[w][row][0] = s1; red[w][row][1] = s2;
            }
        }
    __syncthreads();
    if (tid < 64) {
        float s1 = red[0][tid][0] + red[1][tid][0] + red[2][tid][0] + red[3][tid][0];
        float s2 = red[0][tid][1] + red[1][tid][1] + red[2][tid][1] + red[3][tid][1];
        float mu = s1 * (1.f / DH);
        float var = s2 * (1.f / DH) - mu * mu;
        stats[tid][0] = mu;
        stats[tid][1] = rsqrtf(var + 1e-5f);
    }
    __syncthreads();
#pragma unroll
    for (int nt = 0; nt < 2; ++nt) {
        int col = w * 32 + nt * 16 + mr;
        float gc = g[col], bc = bb[col];
#pragma unroll
        for (int mt = 0; mt < 4; ++mt)
#pragma unroll
            for (int r4 = 0; r4 < 4; ++r4) {
                int row = mt * 16 + q * 4 + r4;
                int gr = row0 + row;
                if (gr < M) {
                    float yv = (acc3[mt][nt][r4] - stats[row][0]) * stats[row][1] * gc + bc;
                    unsigned short yb = f2bf(yv);
                    h[(size_t)gr * DH + col] = yv;
                    hbf[(size_t)gr * DH + col] = yb;
                    HID[row * 136 + col] = yb;
                }
            }
    }
    __syncthreads();

    floatx4 acc4[4][4] = {};
#pragma unroll
    for (int kc = 0; kc < 4; ++kc) {
        const int ko = kc * 32 + q * 8;
        shortx8 a[4], b[4];
#pragma unroll
        for (int mt = 0; mt < 4; ++mt)
            a[mt] = *reinterpret_cast<const shortx8*>(HID + (mt * 16 + mr) * 136 + ko);
#pragma unroll
        for (int nt = 0; nt < 4; ++nt) {
            int ocol = w * 64 + nt * 16 + mr;
            b[nt] = *reinterpret_cast<const shortx8*>(BT + (size_t)ocol * DH + ko);
        }
#pragma unroll
        for (int mt = 0; mt < 4; ++mt)
#pragma unroll
            for (int nt = 0; nt < 4; ++nt)
                acc4[mt][nt] = __builtin_amdgcn_mfma_f32_16x16x32_bf16(a[mt], b[nt], acc4[mt][nt], 0, 0, 0);
    }
#pragma unroll
    for (int nt = 0; nt < 4; ++nt) {
        int ocol = w * 64 + nt * 16 + mr;
        int col = ocol & (DH - 1);
#pragma unroll
        for (int mt = 0; mt < 4; ++mt)
#pragma unroll
            for (int r4 = 0; r4 < 4; ++r4) {
                int gr = row0 + mt * 16 + q * 4 + r4;
                if (gr < M) {
                    if (LAST) {
                        float* O = (ocol < DH) ? O1f : O2f;
                        O[(size_t)gr * DH + col] = acc4[mt][nt][r4];
                    } else {
                        unsigned short* O = (ocol < DH) ? O1b : O2b;
                        O[(size_t)gr * DH + col] = f2bf(acc4[mt][nt][r4]);
                    }
                }
            }
    }
}

// ---- pair head: 2 pairs per wave (32-lane halves, float4 channels), fp32 tables ----
__global__ __launch_bounds__(256)
void pair_kernel(const float* __restrict__ Hu, const float* __restrict__ Hv,
                 const int* __restrict__ pairs, const float* __restrict__ xyr,
                 const float* __restrict__ ehw1c,
                 const float* __restrict__ eb1, const float* __restrict__ ew2,
                 const float* __restrict__ eb2,
                 float* __restrict__ out, int P) {
    int half = threadIdx.x >> 5;
    int p = blockIdx.x * 8 + half;
    bool valid = (p < P);
    int pp = valid ? p : (P - 1);
    int u = pairs[2 * pp], v = pairs[2 * pp + 1];
    float ru = xyr[3 * u + 2], rv_ = xyr[3 * v + 2];
    float dx = xyr[3 * u] - xyr[3 * v];
    float dy = xyr[3 * u + 1] - xyr[3 * v + 1];
    float dist = sqrtf(dx * dx + dy * dy + 1e-8f);
    float adr = fabsf(ru - rv_);
    int c = (threadIdx.x & 31) * 4;
    floatx4 hu = *(const floatx4*)(Hu + (size_t)u * DH + c);
    floatx4 hv = *(const floatx4*)(Hv + (size_t)v * DH + c);
    floatx4 bv = *(const floatx4*)(eb1 + c);
    floatx4 wv = *(const floatx4*)(ew2 + c);
    floatx4 c0 = *(const floatx4*)(ehw1c + 0 * DH + c);
    floatx4 c1 = *(const floatx4*)(ehw1c + 1 * DH + c);
    floatx4 c2 = *(const floatx4*)(ehw1c + 2 * DH + c);
    floatx4 c3 = *(const floatx4*)(ehw1c + 3 * DH + c);
    floatx4 px = hu + hv + bv + ru * c0 + rv_ * c1 + dist * c2 + adr * c3;
    float val = fast_silu(px.x) * wv.x + fast_silu(px.y) * wv.y +
                fast_silu(px.z) * wv.z + fast_silu(px.w) * wv.w;
#pragma unroll
    for (int m = 1; m < 32; m <<= 1) val += __shfl_xor(val, m);
    if (((threadIdx.x & 31) == 0) && valid) out[p] = val + eb2[0];
}

extern "C" void kernel_launch(void* const* d_in, const int* in_sizes, int n_in,
                              void* d_out, int out_size, void* d_ws, size_t ws_size,
                              hipStream_t stream) {
    const float* xyr     = (const float*)d_in[0];
    const int*   eidx    = (const int*)d_in[1];
    const int*   pairs   = (const int*)d_in[2];
    const float* node_w1 = (const float*)d_in[3];
    const float* node_b1 = (const float*)d_in[4];
    const float* node_w2 = (const float*)d_in[5];
    const float* node_b2 = (const float*)d_in[6];
    const float* pm_w1   = (const float*)d_in[7];
    const float* pm_b1   = (const float*)d_in[8];
    const float* pm_w2   = (const float*)d_in[9];
    const float* pm_b2   = (const float*)d_in[10];
    const float* ph_w1   = (const float*)d_in[11];
    const float* ph_b1   = (const float*)d_in[12];
    const float* ph_w2   = (const float*)d_in[13];
    const float* ph_b2   = (const float*)d_in[14];
    const float* ln_g    = (const float*)d_in[15];
    const float* ln_b    = (const float*)d_in[16];
    const float* eh_w1   = (const float*)d_in[17];
    const float* eh_b1   = (const float*)d_in[18];
    const float* eh_w2   = (const float*)d_in[19];
    const float* eh_b2   = (const float*)d_in[20];

    const int N = in_sizes[0] / 3;
    const int E = in_sizes[1] / 2;
    const int P = in_sizes[2] / 2;
    const int* src = eidx;
    const int* dst = eidx + E;

    char* ws = (char*)d_ws;
    size_t off = 0;
    auto alloc = [&](size_t bytes) -> char* {
        char* p = ws + off;
        off += (bytes + 255) & ~(size_t)255;
        return p;
    };
    unsigned short* W1abT = (unsigned short*)alloc((size_t)3 * 256 * 128 * 2);
    unsigned short* PB1T  = (unsigned short*)alloc((size_t)3 * 128 * 256 * 2);
    unsigned short* PH2T  = (unsigned short*)alloc((size_t)3 * 128 * 128 * 2);
    unsigned short* EHT   = (unsigned short*)alloc((size_t)256 * 128 * 2);
    float*          cvec  = (float*)alloc((size_t)3 * 128 * 4);
    unsigned short* Ttab  = (unsigned short*)alloc((size_t)3 * (TGRID + 1) * 128 * 2);
    float*          h     = (float*)alloc((size_t)N * DH * 4);
    unsigned short* hbf   = (unsigned short*)alloc((size_t)N * DH * 2);
    unsigned short* Hsb   = (unsigned short*)alloc((size_t)N * DH * 2);
    unsigned short* Hdb   = (unsigned short*)alloc((size_t)N * DH * 2);
    float*          Hs    = (float*)alloc((size_t)N * DH * 4);
    float*          Hd    = (float*)alloc((size_t)N * DH * 4);
    unsigned int*   Sbf   = (unsigned int*)alloc((size_t)N * 64 * 4);
    int*            epack = (int*)alloc((size_t)(E + 32) * 4);
    int*            cnt   = (int*)alloc((size_t)N * 4);
    int*            rs    = (int*)alloc((size_t)(N + 1) * 4);
    int*            cursor= (int*)alloc((size_t)N * 4);
    float*          cntf  = (float*)alloc((size_t)N * 4);
    (void)ws_size; (void)n_in; (void)out_size;

    const int PREP_TOT = 3 * 256 * 128 + 256 * 128 + 3 * 128 * 256 + 3 * 128 * 128
                       + 3 * 128 + 3 * (TGRID + 1) * 128 + N;
    const int PB = (PREP_TOT + 255) / 256;
    const int NODEB = (N + 31) / 32;
    prep_all_kernel<<<PB + NODEB, 256, 0, stream>>>(pm_w1, eh_w1, ph_w1, ph_w2,
                                                    pm_w2, pm_b2,
                                                    W1abT, EHT, PB1T, PH2T,
                                                    cvec, Ttab, cnt,
                                                    xyr, node_w1, node_b1, node_w2, node_b2,
                                                    h, hbf, N, PB);

    count_kernel<<<(E + 255) / 256, 256, 0, stream>>>(dst, cnt, E);
    scan_kernel<<<1, 1024, 0, stream>>>(cnt, rs, cursor, cntf, N);
    fill_kernel<<<(E + 255) / 256, 256, 0, stream>>>(src, dst, cursor, xyr, epack, E);

    const int MB = (N + 63) / 64;
    proj_kernel<<<MB, 256, 0, stream>>>(hbf, W1abT, Hsb, Hdb, N);
    for (int l = 0; l < 3; ++l) {
        edge_kernel<<<N, 64, 0, stream>>>(Hsb, Hdb, Ttab + (size_t)l * (TGRID + 1) * 128,
                                          pm_b1 + l * DH, rs, epack, Sbf, N);
        if (l < 2) {
            upd_kernel<0><<<MB, 256, 0, stream>>>(hbf, (const unsigned short*)Sbf, h,
                                                  PB1T + (size_t)l * 128 * 256, ph_b1 + l * DH,
                                                  cvec + l * 128, cntf,
                                                  PH2T + (size_t)l * 128 * 128, ph_b2 + l * DH,
                                                  ln_g + l * DH, ln_b + l * DH,
                                                  W1abT + (size_t)(l + 1) * 256 * 128,
                                                  Hsb, Hdb, nullptr, nullptr, N);
        } else {
            upd_kernel<1><<<MB, 256, 0, stream>>>(hbf, (const unsigned short*)Sbf, h,
                                                  PB1T + (size_t)l * 128 * 256, ph_b1 + l * DH,
                                                  cvec + l * 128, cntf,
                                                  PH2T + (size_t)l * 128 * 128, ph_b2 + l * DH,
                                                  ln_g + l * DH, ln_b + l * DH,
                                                  EHT, nullptr, nullptr, Hs, Hd, N);
        }
    }

    pair_kernel<<<(P + 7) / 8, 256, 0, stream>>>(Hs, Hd, pairs, xyr, eh_w1 + 256 * DH,
                                                 eh_b1, eh_w2, eh_b2, (float*)d_out, P);
}

// Round 15
// 331.716 us; speedup vs baseline: 1.0338x; 1.0338x over previous
//
#include <hip/hip_runtime.h>

#define DH 128
#define RMAXF 1.41421356237309515f
#define TGRID 2048

typedef float  floatx4 __attribute__((ext_vector_type(4)));
typedef float  floatx2 __attribute__((ext_vector_type(2)));
typedef short  shortx8 __attribute__((ext_vector_type(8)));
typedef int    intx4  __attribute__((ext_vector_type(4)));

__device__ __forceinline__ unsigned short f2bf(float f) {
    unsigned u = __builtin_bit_cast(unsigned, f);
    u += 0x7fffu + ((u >> 16) & 1u);
    return (unsigned short)(u >> 16);
}
__device__ __forceinline__ floatx2 unpack_bf2(unsigned u) {
    floatx2 r;
    r.x = __builtin_bit_cast(float, u << 16);
    r.y = __builtin_bit_cast(float, u & 0xffff0000u);
    return r;
}
__device__ __forceinline__ float fast_silu(float x) {
    return x * __builtin_amdgcn_rcpf(1.f + __expf(-x));
}

// ---- one prep kernel: bf16 transposed weights (W2P/cvec dots inline), bf16 NN RBF table,
//      cnt zero, PLUS node-encoder tail blocks ----
__global__ __launch_bounds__(256)
void prep_all_kernel(const float* __restrict__ pm_w1, const float* __restrict__ eh_w1,
                     const float* __restrict__ ph_w1, const float* __restrict__ ph_w2,
                     const float* __restrict__ pm_w2, const float* __restrict__ pm_b2,
                     unsigned short* __restrict__ W1abT, unsigned short* __restrict__ EHT,
                     unsigned short* __restrict__ PB1T, unsigned short* __restrict__ PH2T,
                     float* __restrict__ cvec, unsigned short* __restrict__ Tb,
                     int* __restrict__ cnt,
                     const float* __restrict__ xyr,
                     const float* __restrict__ nw1, const float* __restrict__ nb1,
                     const float* __restrict__ nw2, const float* __restrict__ nb2,
                     float* __restrict__ h, unsigned short* __restrict__ hbf,
                     int N, int PB) {
    if ((int)blockIdx.x >= PB) {
        __shared__ float xs[32][3];
        __shared__ float hid[32][DH];
        const int g = threadIdx.x >> 7;
        const int t = threadIdx.x & 127;
        const int n0 = ((int)blockIdx.x - PB) * 32 + g * 16;
        if (t < 48) {
            int i = t / 3, j = t - 3 * (t / 3);
            int n = n0 + i; if (n >= N) n = N - 1;
            xs[g * 16 + i][j] = xyr[3 * n + j];
        }
        __syncthreads();
        int col = t;
        float w10 = nw1[col], w11 = nw1[DH + col], w12 = nw1[2 * DH + col];
        float bb = nb1[col];
#pragma unroll
        for (int i = 0; i < 16; ++i) {
            float v = bb + xs[g * 16 + i][0] * w10 + xs[g * 16 + i][1] * w11 + xs[g * 16 + i][2] * w12;
            hid[g * 16 + i][col] = fast_silu(v);
        }
        __syncthreads();
        float a[16];
#pragma unroll
        for (int i = 0; i < 16; ++i) a[i] = nb2[col];
        for (int j = 0; j < DH; ++j) {
            float wv = nw2[j * DH + col];
#pragma unroll
            for (int i = 0; i < 16; ++i) a[i] += hid[g * 16 + i][j] * wv;
        }
        for (int i = 0; i < 16; ++i) {
            int n = n0 + i;
            if (n < N) {
                h[(size_t)n * DH + col] = a[i];
                hbf[(size_t)n * DH + col] = f2bf(a[i]);
            }
        }
        return;
    }
    int idx = blockIdx.x * 256 + threadIdx.x;
    const int nA = 3 * 256 * 128;
    const int nB = 256 * 128;
    const int nC = 3 * 128 * 256;
    const int nD = 3 * 128 * 128;
    const int nE = 3 * 128;
    const int nT = 3 * (TGRID + 1) * 128;
    if (idx < nA) {
        int l = idx / (256 * 128);
        int rem = idx - l * 256 * 128;
        int j = rem >> 7, k = rem & 127;
        int srow = ((j >> 7) << 7) + k;
        W1abT[idx] = f2bf(pm_w1[(size_t)l * 272 * 128 + (size_t)srow * 128 + (j & 127)]);
        return;
    }
    idx -= nA;
    if (idx < nB) {
        int j = idx >> 7, k = idx & 127;
        int srow = ((j >> 7) << 7) + k;
        EHT[idx] = f2bf(eh_w1[(size_t)srow * 128 + (j & 127)]);
        return;
    }
    idx -= nB;
    if (idx < nC) {
        int l = idx / (128 * 256);
        int rem = idx - l * 128 * 256;
        int j = rem >> 8, k = rem & 255;
        float v;
        if (k < 128) {
            v = ph_w1[(size_t)l * 256 * 128 + (size_t)k * 128 + j];
        } else {
            const float* w2r = pm_w2 + (size_t)l * 128 * 128 + (size_t)(k - 128) * 128;
            const float* p1b = ph_w1 + (size_t)l * 256 * 128 + (size_t)128 * 128 + j;
            float s = 0.f;
            for (int m = 0; m < 128; ++m) s += w2r[m] * p1b[(size_t)m * 128];
            v = s;
        }
        PB1T[idx] = f2bf(v);
        return;
    }
    idx -= nC;
    if (idx < nD) {
        int l = idx / (128 * 128);
        int rem = idx - l * 128 * 128;
        int j = rem >> 7, k = rem & 127;
        PH2T[idx] = f2bf(ph_w2[(size_t)l * 128 * 128 + (size_t)k * 128 + j]);
        return;
    }
    idx -= nD;
    if (idx < nE) {
        int l = idx >> 7, o = idx & 127;
        const float* b2 = pm_b2 + l * 128;
        const float* p1b = ph_w1 + (size_t)l * 256 * 128 + (size_t)128 * 128 + o;
        float s = 0.f;
        for (int m = 0; m < 128; ++m) s += b2[m] * p1b[(size_t)m * 128];
        cvec[idx] = s;
        return;
    }
    idx -= nE;
    if (idx < nT) {
        int l = idx / ((TGRID + 1) * 128);
        int rem = idx - l * (TGRID + 1) * 128;
        int i = rem >> 7, ch = rem & 127;
        float r = (float)i * (RMAXF / (float)TGRID);
        const float step = RMAXF / 15.f;
        const float gamma = 56.25f;
        const float* w1c = pm_w1 + (size_t)l * 272 * 128 + (size_t)256 * 128 + ch;
        float s = 0.f;
#pragma unroll
        for (int k = 0; k < 16; ++k) {
            float d = r - (float)k * step;
            s += expf(-gamma * d * d) * w1c[(size_t)k * 128];
        }
        Tb[idx] = f2bf(s);
        return;
    }
    idx -= nT;
    if (idx < N) cnt[idx] = 0;
}

// ---- CSR build ----
__global__ void count_kernel(const int* __restrict__ dst, int* __restrict__ cnt, int E) {
    int e = blockIdx.x * 256 + threadIdx.x;
    if (e < E) atomicAdd(&cnt[dst[e]], 1);
}
__global__ __launch_bounds__(1024)
void scan_kernel(const int* __restrict__ cnt, int* __restrict__ rs, int* __restrict__ cursor,
                 float* __restrict__ cntf, int N) {
    __shared__ int ps[1024];
    const int CH = 16;
    int t = threadIdx.x;
    int base = t * CH;
    int loc[CH];
    int s = 0;
#pragma unroll
    for (int j = 0; j < CH; ++j) {
        int i = base + j;
        int v = (i < N) ? cnt[i] : 0;
        if (i < N) cntf[i] = (float)v;
        loc[j] = s; s += v;
    }
    ps[t] = s;
    __syncthreads();
    for (int off = 1; off < 1024; off <<= 1) {
        int v = (t >= off) ? ps[t - off] : 0;
        __syncthreads();
        ps[t] += v;
        __syncthreads();
    }
    int pre = (t > 0) ? ps[t - 1] : 0;
#pragma unroll
    for (int j = 0; j < CH; ++j) {
        int i = base + j;
        if (i < N) { int v = pre + loc[j]; rs[i] = v; cursor[i] = v; }
    }
    if (t == 0) rs[N] = ps[1023];
}
// ---- fill: per CSR slot store packed {src | T-row-index<<18}; pads 32 tail slots ----
__global__ void fill_kernel(const int* __restrict__ src, const int* __restrict__ dst,
                            int* __restrict__ cursor, const float* __restrict__ xyr,
                            int* __restrict__ epack, int E) {
    int e = blockIdx.x * 256 + threadIdx.x;
    if (e < 32) epack[E + e] = 0;
    if (e >= E) return;
    int s = src[e], d = dst[e];
    int p = atomicAdd(&cursor[d], 1);
    float dx = xyr[3 * s] - xyr[3 * d];
    float dy = xyr[3 * s + 1] - xyr[3 * d + 1];
    float r = sqrtf(dx * dx + dy * dy + 1e-8f);
    int ti = (int)(r * ((float)TGRID / RMAXF) + 0.5f);
    ti = (ti > TGRID) ? TGRID : ti;
    epack[p] = s | (ti << 18);
}

// ---- proj (layer-0): Hsb||Hdb (bf16) = hbf @ W1abT^T ----
__global__ __launch_bounds__(256)
void proj_kernel(const unsigned short* __restrict__ Abf,
                 const unsigned short* __restrict__ BT,
                 unsigned short* __restrict__ O1b, unsigned short* __restrict__ O2b, int M) {
    const int tid = threadIdx.x;
    const int w = tid >> 6, lane = tid & 63;
    const int mr = lane & 15, q = lane >> 4;
    const int row0 = blockIdx.x * 64;
    floatx4 acc[4][4] = {};
#pragma unroll
    for (int kc = 0; kc < 4; ++kc) {
        const int ko = kc * 32 + q * 8;
        shortx8 a[4], b[4];
#pragma unroll
        for (int mt = 0; mt < 4; ++mt) {
            int r = row0 + mt * 16 + mr; if (r >= M) r = M - 1;
            a[mt] = *reinterpret_cast<const shortx8*>(Abf + (size_t)r * DH + ko);
        }
#pragma unroll
        for (int nt = 0; nt < 4; ++nt) {
            int ocol = w * 64 + nt * 16 + mr;
            b[nt] = *reinterpret_cast<const shortx8*>(BT + (size_t)ocol * DH + ko);
        }
#pragma unroll
        for (int mt = 0; mt < 4; ++mt)
#pragma unroll
            for (int nt = 0; nt < 4; ++nt)
                acc[mt][nt] = __builtin_amdgcn_mfma_f32_16x16x32_bf16(a[mt], b[nt], acc[mt][nt], 0, 0, 0);
    }
#pragma unroll
    for (int nt = 0; nt < 4; ++nt) {
        int ocol = w * 64 + nt * 16 + mr;
        unsigned short* O = (ocol < DH) ? O1b : O2b;
        int col = ocol & (DH - 1);
#pragma unroll
        for (int mt = 0; mt < 4; ++mt)
#pragma unroll
            for (int r4 = 0; r4 < 4; ++r4) {
                int gr = row0 + mt * 16 + q * 4 + r4;
                if (gr < M) O[(size_t)gr * DH + col] = f2bf(acc[mt][nt][r4]);
            }
    }
}

// ---- edge stream + aggregate: ONE WAVE = ONE NODE = ONE BLOCK; batch-4 prefetch,
//      mask hoisted out of hot loop (full batches unmasked, single masked tail) ----
__global__ __launch_bounds__(64)
void edge_kernel(const unsigned short* __restrict__ Hsb, const unsigned short* __restrict__ Hdb,
                 const unsigned short* __restrict__ Tb,   // [TGRID+1][128] bf16 for this layer
                 const float* __restrict__ b1,
                 const int* __restrict__ rs, const int* __restrict__ epack,
                 unsigned int* __restrict__ Sbf, int N) {
    const int n = blockIdx.x;
    const int lane = threadIdx.x;
    const int c = lane * 2;
    floatx2 hdn = unpack_bf2(*(const unsigned*)(Hdb + (size_t)n * DH + c))
                + *(const floatx2*)(b1 + c);
    const int s = rs[n], e = rs[n + 1];
    floatx2 acc = {0.f, 0.f};
    const int cnt = e - s;
    if (cnt > 0) {
        const int nb = (cnt + 3) >> 2;
        intx4 pk = __builtin_nontemporal_load((const intx4*)(epack + s));
        unsigned hu[4], tw[4];
        {
            int p0 = pk.x, p1 = pk.y, p2 = pk.z, p3 = pk.w;
            hu[0] = *(const unsigned*)(Hsb + (size_t)(p0 & 0x3ffff) * DH + c);
            hu[1] = *(const unsigned*)(Hsb + (size_t)(p1 & 0x3ffff) * DH + c);
            hu[2] = *(const unsigned*)(Hsb + (size_t)(p2 & 0x3ffff) * DH + c);
            hu[3] = *(const unsigned*)(Hsb + (size_t)(p3 & 0x3ffff) * DH + c);
            tw[0] = *(const unsigned*)(Tb + (size_t)(((unsigned)p0) >> 18) * DH + c);
            tw[1] = *(const unsigned*)(Tb + (size_t)(((unsigned)p1) >> 18) * DH + c);
            tw[2] = *(const unsigned*)(Tb + (size_t)(((unsigned)p2) >> 18) * DH + c);
            tw[3] = *(const unsigned*)(Tb + (size_t)(((unsigned)p3) >> 18) * DH + c);
        }
        // full batches (all 4 edges valid) — no mask
        for (int b = 0; b < nb - 1; ++b) {
            const int j = s + b * 4;
            intx4 pkN = __builtin_nontemporal_load((const intx4*)(epack + j + 4));
            unsigned huN[4], twN[4];
            {
                int p0 = pkN.x, p1 = pkN.y, p2 = pkN.z, p3 = pkN.w;
                huN[0] = *(const unsigned*)(Hsb + (size_t)(p0 & 0x3ffff) * DH + c);
                huN[1] = *(const unsigned*)(Hsb + (size_t)(p1 & 0x3ffff) * DH + c);
                huN[2] = *(const unsigned*)(Hsb + (size_t)(p2 & 0x3ffff) * DH + c);
                huN[3] = *(const unsigned*)(Hsb + (size_t)(p3 & 0x3ffff) * DH + c);
                twN[0] = *(const unsigned*)(Tb + (size_t)(((unsigned)p0) >> 18) * DH + c);
                twN[1] = *(const unsigned*)(Tb + (size_t)(((unsigned)p1) >> 18) * DH + c);
                twN[2] = *(const unsigned*)(Tb + (size_t)(((unsigned)p2) >> 18) * DH + c);
                twN[3] = *(const unsigned*)(Tb + (size_t)(((unsigned)p3) >> 18) * DH + c);
            }
#pragma unroll
            for (int i = 0; i < 4; ++i) {
                floatx2 pre = unpack_bf2(hu[i]) + hdn + unpack_bf2(tw[i]);
                floatx2 sg;
                sg.x = __builtin_amdgcn_rcpf(1.f + __expf(-pre.x));
                sg.y = __builtin_amdgcn_rcpf(1.f + __expf(-pre.y));
                acc += pre * sg;
            }
#pragma unroll
            for (int i = 0; i < 4; ++i) { hu[i] = huN[i]; tw[i] = twN[i]; }
        }
        // tail batch — masked
        {
            const int j = s + (nb - 1) * 4;
#pragma unroll
            for (int i = 0; i < 4; ++i) {
                floatx2 pre = unpack_bf2(hu[i]) + hdn + unpack_bf2(tw[i]);
                floatx2 sg;
                sg.x = __builtin_amdgcn_rcpf(1.f + __expf(-pre.x));
                sg.y = __builtin_amdgcn_rcpf(1.f + __expf(-pre.y));
                float msk = (j + i < e) ? 1.f : 0.f;
                acc += (pre * sg) * msk;
            }
        }
    }
    unsigned lo = f2bf(acc.x), hi = f2bf(acc.y);
    Sbf[(size_t)n * 64 + lane] = lo | (hi << 16);
}

// ---- node update + fused next-layer projection; 32-row tiles (R11/R12 differential: −3.6 µs) ----
template<int LAST>
__global__ __launch_bounds__(256)
void upd_kernel(unsigned short* hbf,
                const unsigned short* __restrict__ Sbf16,
                float* h,
                const unsigned short* __restrict__ PB1T,   // [128][256]
                const float* __restrict__ b1v,
                const float* __restrict__ cvec,            // [128]
                const float* __restrict__ cntf,
                const unsigned short* __restrict__ P2T,    // [128][128]
                const float* __restrict__ b2v,
                const float* __restrict__ g, const float* __restrict__ bb,
                const unsigned short* __restrict__ BT,     // [256][128] next-proj
                unsigned short* __restrict__ O1b, unsigned short* __restrict__ O2b,  // LAST=0
                float* __restrict__ O1f, float* __restrict__ O2f,                    // LAST=1
                int M) {
    __shared__ unsigned short HID[32 * 136];
    __shared__ float red[4][32][2];
    __shared__ float stats[32][2];
    __shared__ float cntL[32];
    const int tid = threadIdx.x;
    const int w = tid >> 6, lane = tid & 63;
    const int mr = lane & 15, q = lane >> 4;
    const int row0 = blockIdx.x * 32;

    if (tid < 32) {
        int r = row0 + tid;
        cntL[tid] = (r < M) ? cntf[r] : 0.f;
    }
    __syncthreads();

    floatx4 acc[2][2] = {};
#pragma unroll
    for (int kc = 0; kc < 8; ++kc) {
        const int ko = kc * 32 + q * 8;
        shortx8 a[2], bfr[2];
#pragma unroll
        for (int mt = 0; mt < 2; ++mt) {
            int r = row0 + mt * 16 + mr; if (r >= M) r = M - 1;
            const unsigned short* sp = (ko < DH) ? (hbf + (size_t)r * DH + ko)
                                                 : (Sbf16 + (size_t)r * DH + (ko - DH));
            a[mt] = *reinterpret_cast<const shortx8*>(sp);
        }
#pragma unroll
        for (int nt = 0; nt < 2; ++nt)
            bfr[nt] = *reinterpret_cast<const shortx8*>(PB1T + (size_t)(w * 32 + nt * 16 + mr) * 256 + ko);
#pragma unroll
        for (int mt = 0; mt < 2; ++mt)
#pragma unroll
            for (int nt = 0; nt < 2; ++nt)
                acc[mt][nt] = __builtin_amdgcn_mfma_f32_16x16x32_bf16(a[mt], bfr[nt], acc[mt][nt], 0, 0, 0);
    }
#pragma unroll
    for (int nt = 0; nt < 2; ++nt) {
        int col = w * 32 + nt * 16 + mr;
        float bv = b1v[col], cv = cvec[col];
#pragma unroll
        for (int mt = 0; mt < 2; ++mt)
#pragma unroll
            for (int r4 = 0; r4 < 4; ++r4) {
                int row = mt * 16 + q * 4 + r4;
                HID[row * 136 + col] = f2bf(fast_silu(acc[mt][nt][r4] + bv + cntL[row] * cv));
            }
    }
    __syncthreads();

    floatx4 acc3[2][2] = {};
#pragma unroll
    for (int kc = 0; kc < 4; ++kc) {
        const int ko = kc * 32 + q * 8;
        shortx8 a[2], bfr[2];
#pragma unroll
        for (int mt = 0; mt < 2; ++mt)
            a[mt] = *reinterpret_cast<const shortx8*>(HID + (mt * 16 + mr) * 136 + ko);
#pragma unroll
        for (int nt = 0; nt < 2; ++nt)
            bfr[nt] = *reinterpret_cast<const shortx8*>(P2T + (size_t)(w * 32 + nt * 16 + mr) * DH + ko);
#pragma unroll
        for (int mt = 0; mt < 2; ++mt)
#pragma unroll
            for (int nt = 0; nt < 2; ++nt)
                acc3[mt][nt] = __builtin_amdgcn_mfma_f32_16x16x32_bf16(a[mt], bfr[nt], acc3[mt][nt], 0, 0, 0);
    }
#pragma unroll
    for (int nt = 0; nt < 2; ++nt) {
        int col = w * 32 + nt * 16 + mr;
        float b2c = b2v[col];
#pragma unroll
        for (int mt = 0; mt < 2; ++mt)
#pragma unroll
            for (int r4 = 0; r4 < 4; ++r4) {
                int gr = row0 + mt * 16 + q * 4 + r4;
                float hv = (gr < M) ? h[(size_t)gr * DH + col] : 0.f;
                acc3[mt][nt][r4] = acc3[mt][nt][r4] + b2c + hv;
            }
    }
#pragma unroll
    for (int mt = 0; mt < 2; ++mt)
#pragma unroll
        for (int r4 = 0; r4 < 4; ++r4) {
            float y0 = acc3[mt][0][r4], y1 = acc3[mt][1][r4];
            float s1 = y0 + y1, s2 = y0 * y0 + y1 * y1;
#pragma unroll
            for (int m = 1; m < 16; m <<= 1) {
                s1 += __shfl_xor(s1, m);
                s2 += __shfl_xor(s2, m);
            }
            if (mr == 0) {
                int row = mt * 16 + q * 4 + r4;
                red[w][row][0] = s1; red[w][row][1] = s2;
            }
        }
    __syncthreads();
    if (tid < 32) {
        float s1 = red[0][tid][0] + red[1][tid][0] + red[2][tid][0] + red[3][tid][0];
        float s2 = red[0][tid][1] + red[1][tid][1] + red[2][tid][1] + red[3][tid][1];
        float mu = s1 * (1.f / DH);
        float var = s2 * (1.f / DH) - mu * mu;
        stats[tid][0] = mu;
        stats[tid][1] = rsqrtf(var + 1e-5f);
    }
    __syncthreads();
#pragma unroll
    for (int nt = 0; nt < 2; ++nt) {
        int col = w * 32 + nt * 16 + mr;
        float gc = g[col], bc = bb[col];
#pragma unroll
        for (int mt = 0; mt < 2; ++mt)
#pragma unroll
            for (int r4 = 0; r4 < 4; ++r4) {
                int row = mt * 16 + q * 4 + r4;
                int gr = row0 + row;
                if (gr < M) {
                    float yv = (acc3[mt][nt][r4] - stats[row][0]) * stats[row][1] * gc + bc;
                    unsigned short yb = f2bf(yv);
                    h[(size_t)gr * DH + col] = yv;
                    hbf[(size_t)gr * DH + col] = yb;
                    HID[row * 136 + col] = yb;
                }
            }
    }
    __syncthreads();

    floatx4 acc4[2][4] = {};
#pragma unroll
    for (int kc = 0; kc < 4; ++kc) {
        const int ko = kc * 32 + q * 8;
        shortx8 a[2], b[4];
#pragma unroll
        for (int mt = 0; mt < 2; ++mt)
            a[mt] = *reinterpret_cast<const shortx8*>(HID + (mt * 16 + mr) * 136 + ko);
#pragma unroll
        for (int nt = 0; nt < 4; ++nt) {
            int ocol = w * 64 + nt * 16 + mr;
            b[nt] = *reinterpret_cast<const shortx8*>(BT + (size_t)ocol * DH + ko);
        }
#pragma unroll
        for (int mt = 0; mt < 2; ++mt)
#pragma unroll
            for (int nt = 0; nt < 4; ++nt)
                acc4[mt][nt] = __builtin_amdgcn_mfma_f32_16x16x32_bf16(a[mt], b[nt], acc4[mt][nt], 0, 0, 0);
    }
#pragma unroll
    for (int nt = 0; nt < 4; ++nt) {
        int ocol = w * 64 + nt * 16 + mr;
        int col = ocol & (DH - 1);
#pragma unroll
        for (int mt = 0; mt < 2; ++mt)
#pragma unroll
            for (int r4 = 0; r4 < 4; ++r4) {
                int gr = row0 + mt * 16 + q * 4 + r4;
                if (gr < M) {
                    if (LAST) {
                        float* O = (ocol < DH) ? O1f : O2f;
                        O[(size_t)gr * DH + col] = acc4[mt][nt][r4];
                    } else {
                        unsigned short* O = (ocol < DH) ? O1b : O2b;
                        O[(size_t)gr * DH + col] = f2bf(acc4[mt][nt][r4]);
                    }
                }
            }
    }
}

// ---- pair head: 2 pairs per wave (32-lane halves, float4 channels), fp32 tables ----
__global__ __launch_bounds__(256)
void pair_kernel(const float* __restrict__ Hu, const float* __restrict__ Hv,
                 const int* __restrict__ pairs, const float* __restrict__ xyr,
                 const float* __restrict__ ehw1c,
                 const float* __restrict__ eb1, const float* __restrict__ ew2,
                 const float* __restrict__ eb2,
                 float* __restrict__ out, int P) {
    int half = threadIdx.x >> 5;
    int p = blockIdx.x * 8 + half;
    bool valid = (p < P);
    int pp = valid ? p : (P - 1);
    int u = pairs[2 * pp], v = pairs[2 * pp + 1];
    float ru = xyr[3 * u + 2], rv_ = xyr[3 * v + 2];
    float dx = xyr[3 * u] - xyr[3 * v];
    float dy = xyr[3 * u + 1] - xyr[3 * v + 1];
    float dist = sqrtf(dx * dx + dy * dy + 1e-8f);
    float adr = fabsf(ru - rv_);
    int c = (threadIdx.x & 31) * 4;
    floatx4 hu = *(const floatx4*)(Hu + (size_t)u * DH + c);
    floatx4 hv = *(const floatx4*)(Hv + (size_t)v * DH + c);
    floatx4 bv = *(const floatx4*)(eb1 + c);
    floatx4 wv = *(const floatx4*)(ew2 + c);
    floatx4 c0 = *(const floatx4*)(ehw1c + 0 * DH + c);
    floatx4 c1 = *(const floatx4*)(ehw1c + 1 * DH + c);
    floatx4 c2 = *(const floatx4*)(ehw1c + 2 * DH + c);
    floatx4 c3 = *(const floatx4*)(ehw1c + 3 * DH + c);
    floatx4 px = hu + hv + bv + ru * c0 + rv_ * c1 + dist * c2 + adr * c3;
    float val = fast_silu(px.x) * wv.x + fast_silu(px.y) * wv.y +
                fast_silu(px.z) * wv.z + fast_silu(px.w) * wv.w;
#pragma unroll
    for (int m = 1; m < 32; m <<= 1) val += __shfl_xor(val, m);
    if (((threadIdx.x & 31) == 0) && valid) out[p] = val + eb2[0];
}

extern "C" void kernel_launch(void* const* d_in, const int* in_sizes, int n_in,
                              void* d_out, int out_size, void* d_ws, size_t ws_size,
                              hipStream_t stream) {
    const float* xyr     = (const float*)d_in[0];
    const int*   eidx    = (const int*)d_in[1];
    const int*   pairs   = (const int*)d_in[2];
    const float* node_w1 = (const float*)d_in[3];
    const float* node_b1 = (const float*)d_in[4];
    const float* node_w2 = (const float*)d_in[5];
    const float* node_b2 = (const float*)d_in[6];
    const float* pm_w1   = (const float*)d_in[7];
    const float* pm_b1   = (const float*)d_in[8];
    const float* pm_w2   = (const float*)d_in[9];
    const float* pm_b2   = (const float*)d_in[10];
    const float* ph_w1   = (const float*)d_in[11];
    const float* ph_b1   = (const float*)d_in[12];
    const float* ph_w2   = (const float*)d_in[13];
    const float* ph_b2   = (const float*)d_in[14];
    const float* ln_g    = (const float*)d_in[15];
    const float* ln_b    = (const float*)d_in[16];
    const float* eh_w1   = (const float*)d_in[17];
    const float* eh_b1   = (const float*)d_in[18];
    const float* eh_w2   = (const float*)d_in[19];
    const float* eh_b2   = (const float*)d_in[20];

    const int N = in_sizes[0] / 3;
    const int E = in_sizes[1] / 2;
    const int P = in_sizes[2] / 2;
    const int* src = eidx;
    const int* dst = eidx + E;

    char* ws = (char*)d_ws;
    size_t off = 0;
    auto alloc = [&](size_t bytes) -> char* {
        char* p = ws + off;
        off += (bytes + 255) & ~(size_t)255;
        return p;
    };
    unsigned short* W1abT = (unsigned short*)alloc((size_t)3 * 256 * 128 * 2);
    unsigned short* PB1T  = (unsigned short*)alloc((size_t)3 * 128 * 256 * 2);
    unsigned short* PH2T  = (unsigned short*)alloc((size_t)3 * 128 * 128 * 2);
    unsigned short* EHT   = (unsigned short*)alloc((size_t)256 * 128 * 2);
    float*          cvec  = (float*)alloc((size_t)3 * 128 * 4);
    unsigned short* Ttab  = (unsigned short*)alloc((size_t)3 * (TGRID + 1) * 128 * 2);
    float*          h     = (float*)alloc((size_t)N * DH * 4);
    unsigned short* hbf   = (unsigned short*)alloc((size_t)N * DH * 2);
    unsigned short* Hsb   = (unsigned short*)alloc((size_t)N * DH * 2);
    unsigned short* Hdb   = (unsigned short*)alloc((size_t)N * DH * 2);
    float*          Hs    = (float*)alloc((size_t)N * DH * 4);
    float*          Hd    = (float*)alloc((size_t)N * DH * 4);
    unsigned int*   Sbf   = (unsigned int*)alloc((size_t)N * 64 * 4);
    int*            epack = (int*)alloc((size_t)(E + 32) * 4);
    int*            cnt   = (int*)alloc((size_t)N * 4);
    int*            rs    = (int*)alloc((size_t)(N + 1) * 4);
    int*            cursor= (int*)alloc((size_t)N * 4);
    float*          cntf  = (float*)alloc((size_t)N * 4);
    (void)ws_size; (void)n_in; (void)out_size;

    const int PREP_TOT = 3 * 256 * 128 + 256 * 128 + 3 * 128 * 256 + 3 * 128 * 128
                       + 3 * 128 + 3 * (TGRID + 1) * 128 + N;
    const int PB = (PREP_TOT + 255) / 256;
    const int NODEB = (N + 31) / 32;
    prep_all_kernel<<<PB + NODEB, 256, 0, stream>>>(pm_w1, eh_w1, ph_w1, ph_w2,
                                                    pm_w2, pm_b2,
                                                    W1abT, EHT, PB1T, PH2T,
                                                    cvec, Ttab, cnt,
                                                    xyr, node_w1, node_b1, node_w2, node_b2,
                                                    h, hbf, N, PB);

    count_kernel<<<(E + 255) / 256, 256, 0, stream>>>(dst, cnt, E);
    scan_kernel<<<1, 1024, 0, stream>>>(cnt, rs, cursor, cntf, N);
    fill_kernel<<<(E + 255) / 256, 256, 0, stream>>>(src, dst, cursor, xyr, epack, E);

    const int MB  = (N + 63) / 64;
    const int MB2 = (N + 31) / 32;
    proj_kernel<<<MB, 256, 0, stream>>>(hbf, W1abT, Hsb, Hdb, N);
    for (int l = 0; l < 3; ++l) {
        edge_kernel<<<N, 64, 0, stream>>>(Hsb, Hdb, Ttab + (size_t)l * (TGRID + 1) * 128,
                                          pm_b1 + l * DH, rs, epack, Sbf, N);
        if (l < 2) {
            upd_kernel<0><<<MB2, 256, 0, stream>>>(hbf, (const unsigned short*)Sbf, h,
                                                   PB1T + (size_t)l * 128 * 256, ph_b1 + l * DH,
                                                   cvec + l * 128, cntf,
                                                   PH2T + (size_t)l * 128 * 128, ph_b2 + l * DH,
                                                   ln_g + l * DH, ln_b + l * DH,
                                                   W1abT + (size_t)(l + 1) * 256 * 128,
                                                   Hsb, Hdb, nullptr, nullptr, N);
        } else {
            upd_kernel<1><<<MB2, 256, 0, stream>>>(hbf, (const unsigned short*)Sbf, h,
                                                   PB1T + (size_t)l * 128 * 256, ph_b1 + l * DH,
                                                   cvec + l * 128, cntf,
                                                   PH2T + (size_t)l * 128 * 128, ph_b2 + l * DH,
                                                   ln_g + l * DH, ln_b + l * DH,
                                                   EHT, nullptr, nullptr, Hs, Hd, N);
        }
    }

    pair_kernel<<<(P + 7) / 8, 256, 0, stream>>>(Hs, Hd, pairs, xyr, eh_w1 + 256 * DH,
                                                 eh_b1, eh_w2, eh_b2, (float*)d_out, P);
}

// Round 16
// 329.436 us; speedup vs baseline: 1.0410x; 1.0069x over previous
//
#include <hip/hip_runtime.h>

#define DH 128
#define RMAXF 1.41421356237309515f
#define TGRID 2048

typedef float  floatx4 __attribute__((ext_vector_type(4)));
typedef float  floatx2 __attribute__((ext_vector_type(2)));
typedef short  shortx8 __attribute__((ext_vector_type(8)));
typedef int    intx4  __attribute__((ext_vector_type(4)));

__device__ __forceinline__ unsigned short f2bf(float f) {
    unsigned u = __builtin_bit_cast(unsigned, f);
    u += 0x7fffu + ((u >> 16) & 1u);
    return (unsigned short)(u >> 16);
}
__device__ __forceinline__ floatx2 unpack_bf2(unsigned u) {
    floatx2 r;
    r.x = __builtin_bit_cast(float, u << 16);
    r.y = __builtin_bit_cast(float, u & 0xffff0000u);
    return r;
}
__device__ __forceinline__ float fast_silu(float x) {
    return x * __builtin_amdgcn_rcpf(1.f + __expf(-x));
}

// ---- one prep kernel: bf16 transposed weights (W2P/cvec dots inline), bf16 NN RBF table,
//      cnt zero, PLUS node-encoder tail blocks ----
__global__ __launch_bounds__(256)
void prep_all_kernel(const float* __restrict__ pm_w1, const float* __restrict__ eh_w1,
                     const float* __restrict__ ph_w1, const float* __restrict__ ph_w2,
                     const float* __restrict__ pm_w2, const float* __restrict__ pm_b2,
                     unsigned short* __restrict__ W1abT, unsigned short* __restrict__ EHT,
                     unsigned short* __restrict__ PB1T, unsigned short* __restrict__ PH2T,
                     float* __restrict__ cvec, unsigned short* __restrict__ Tb,
                     int* __restrict__ cnt,
                     const float* __restrict__ xyr,
                     const float* __restrict__ nw1, const float* __restrict__ nb1,
                     const float* __restrict__ nw2, const float* __restrict__ nb2,
                     float* __restrict__ h, unsigned short* __restrict__ hbf,
                     int N, int PB) {
    if ((int)blockIdx.x >= PB) {
        __shared__ float xs[32][3];
        __shared__ float hid[32][DH];
        const int g = threadIdx.x >> 7;
        const int t = threadIdx.x & 127;
        const int n0 = ((int)blockIdx.x - PB) * 32 + g * 16;
        if (t < 48) {
            int i = t / 3, j = t - 3 * (t / 3);
            int n = n0 + i; if (n >= N) n = N - 1;
            xs[g * 16 + i][j] = xyr[3 * n + j];
        }
        __syncthreads();
        int col = t;
        float w10 = nw1[col], w11 = nw1[DH + col], w12 = nw1[2 * DH + col];
        float bb = nb1[col];
#pragma unroll
        for (int i = 0; i < 16; ++i) {
            float v = bb + xs[g * 16 + i][0] * w10 + xs[g * 16 + i][1] * w11 + xs[g * 16 + i][2] * w12;
            hid[g * 16 + i][col] = fast_silu(v);
        }
        __syncthreads();
        float a[16];
#pragma unroll
        for (int i = 0; i < 16; ++i) a[i] = nb2[col];
        for (int j = 0; j < DH; ++j) {
            float wv = nw2[j * DH + col];
#pragma unroll
            for (int i = 0; i < 16; ++i) a[i] += hid[g * 16 + i][j] * wv;
        }
        for (int i = 0; i < 16; ++i) {
            int n = n0 + i;
            if (n < N) {
                h[(size_t)n * DH + col] = a[i];
                hbf[(size_t)n * DH + col] = f2bf(a[i]);
            }
        }
        return;
    }
    int idx = blockIdx.x * 256 + threadIdx.x;
    const int nA = 3 * 256 * 128;
    const int nB = 256 * 128;
    const int nC = 3 * 128 * 256;
    const int nD = 3 * 128 * 128;
    const int nE = 3 * 128;
    const int nT = 3 * (TGRID + 1) * 128;
    if (idx < nA) {
        int l = idx / (256 * 128);
        int rem = idx - l * 256 * 128;
        int j = rem >> 7, k = rem & 127;
        int srow = ((j >> 7) << 7) + k;
        W1abT[idx] = f2bf(pm_w1[(size_t)l * 272 * 128 + (size_t)srow * 128 + (j & 127)]);
        return;
    }
    idx -= nA;
    if (idx < nB) {
        int j = idx >> 7, k = idx & 127;
        int srow = ((j >> 7) << 7) + k;
        EHT[idx] = f2bf(eh_w1[(size_t)srow * 128 + (j & 127)]);
        return;
    }
    idx -= nB;
    if (idx < nC) {
        int l = idx / (128 * 256);
        int rem = idx - l * 128 * 256;
        int j = rem >> 8, k = rem & 255;
        float v;
        if (k < 128) {
            v = ph_w1[(size_t)l * 256 * 128 + (size_t)k * 128 + j];
        } else {
            const float* w2r = pm_w2 + (size_t)l * 128 * 128 + (size_t)(k - 128) * 128;
            const float* p1b = ph_w1 + (size_t)l * 256 * 128 + (size_t)128 * 128 + j;
            float s = 0.f;
            for (int m = 0; m < 128; ++m) s += w2r[m] * p1b[(size_t)m * 128];
            v = s;
        }
        PB1T[idx] = f2bf(v);
        return;
    }
    idx -= nC;
    if (idx < nD) {
        int l = idx / (128 * 128);
        int rem = idx - l * 128 * 128;
        int j = rem >> 7, k = rem & 127;
        PH2T[idx] = f2bf(ph_w2[(size_t)l * 128 * 128 + (size_t)k * 128 + j]);
        return;
    }
    idx -= nD;
    if (idx < nE) {
        int l = idx >> 7, o = idx & 127;
        const float* b2 = pm_b2 + l * 128;
        const float* p1b = ph_w1 + (size_t)l * 256 * 128 + (size_t)128 * 128 + o;
        float s = 0.f;
        for (int m = 0; m < 128; ++m) s += b2[m] * p1b[(size_t)m * 128];
        cvec[idx] = s;
        return;
    }
    idx -= nE;
    if (idx < nT) {
        int l = idx / ((TGRID + 1) * 128);
        int rem = idx - l * (TGRID + 1) * 128;
        int i = rem >> 7, ch = rem & 127;
        float r = (float)i * (RMAXF / (float)TGRID);
        const float step = RMAXF / 15.f;
        const float gamma = 56.25f;
        const float* w1c = pm_w1 + (size_t)l * 272 * 128 + (size_t)256 * 128 + ch;
        float s = 0.f;
#pragma unroll
        for (int k = 0; k < 16; ++k) {
            float d = r - (float)k * step;
            s += expf(-gamma * d * d) * w1c[(size_t)k * 128];
        }
        Tb[idx] = f2bf(s);
        return;
    }
    idx -= nT;
    if (idx < N) cnt[idx] = 0;
}

// ---- CSR build ----
__global__ void count_kernel(const int* __restrict__ dst, int* __restrict__ cnt, int E) {
    int e = blockIdx.x * 256 + threadIdx.x;
    if (e < E) atomicAdd(&cnt[dst[e]], 1);
}
__global__ __launch_bounds__(1024)
void scan_kernel(const int* __restrict__ cnt, int* __restrict__ rs, int* __restrict__ cursor,
                 float* __restrict__ cntf, int N) {
    __shared__ int ps[1024];
    const int CH = 16;
    int t = threadIdx.x;
    int base = t * CH;
    int loc[CH];
    int s = 0;
#pragma unroll
    for (int j = 0; j < CH; ++j) {
        int i = base + j;
        int v = (i < N) ? cnt[i] : 0;
        if (i < N) cntf[i] = (float)v;
        loc[j] = s; s += v;
    }
    ps[t] = s;
    __syncthreads();
    for (int off = 1; off < 1024; off <<= 1) {
        int v = (t >= off) ? ps[t - off] : 0;
        __syncthreads();
        ps[t] += v;
        __syncthreads();
    }
    int pre = (t > 0) ? ps[t - 1] : 0;
#pragma unroll
    for (int j = 0; j < CH; ++j) {
        int i = base + j;
        if (i < N) { int v = pre + loc[j]; rs[i] = v; cursor[i] = v; }
    }
    if (t == 0) rs[N] = ps[1023];
}
// ---- fill: per CSR slot store packed {src | T-row-index<<18}; pads 32 tail slots ----
__global__ void fill_kernel(const int* __restrict__ src, const int* __restrict__ dst,
                            int* __restrict__ cursor, const float* __restrict__ xyr,
                            int* __restrict__ epack, int E) {
    int e = blockIdx.x * 256 + threadIdx.x;
    if (e < 32) epack[E + e] = 0;
    if (e >= E) return;
    int s = src[e], d = dst[e];
    int p = atomicAdd(&cursor[d], 1);
    float dx = xyr[3 * s] - xyr[3 * d];
    float dy = xyr[3 * s + 1] - xyr[3 * d + 1];
    float r = sqrtf(dx * dx + dy * dy + 1e-8f);
    int ti = (int)(r * ((float)TGRID / RMAXF) + 0.5f);
    ti = (ti > TGRID) ? TGRID : ti;
    epack[p] = s | (ti << 18);
}

// ---- proj (layer-0): Hsb||Hdb (bf16) = hbf @ W1abT^T ----
__global__ __launch_bounds__(256)
void proj_kernel(const unsigned short* __restrict__ Abf,
                 const unsigned short* __restrict__ BT,
                 unsigned short* __restrict__ O1b, unsigned short* __restrict__ O2b, int M) {
    const int tid = threadIdx.x;
    const int w = tid >> 6, lane = tid & 63;
    const int mr = lane & 15, q = lane >> 4;
    const int row0 = blockIdx.x * 64;
    floatx4 acc[4][4] = {};
#pragma unroll
    for (int kc = 0; kc < 4; ++kc) {
        const int ko = kc * 32 + q * 8;
        shortx8 a[4], b[4];
#pragma unroll
        for (int mt = 0; mt < 4; ++mt) {
            int r = row0 + mt * 16 + mr; if (r >= M) r = M - 1;
            a[mt] = *reinterpret_cast<const shortx8*>(Abf + (size_t)r * DH + ko);
        }
#pragma unroll
        for (int nt = 0; nt < 4; ++nt) {
            int ocol = w * 64 + nt * 16 + mr;
            b[nt] = *reinterpret_cast<const shortx8*>(BT + (size_t)ocol * DH + ko);
        }
#pragma unroll
        for (int mt = 0; mt < 4; ++mt)
#pragma unroll
            for (int nt = 0; nt < 4; ++nt)
                acc[mt][nt] = __builtin_amdgcn_mfma_f32_16x16x32_bf16(a[mt], b[nt], acc[mt][nt], 0, 0, 0);
    }
#pragma unroll
    for (int nt = 0; nt < 4; ++nt) {
        int ocol = w * 64 + nt * 16 + mr;
        unsigned short* O = (ocol < DH) ? O1b : O2b;
        int col = ocol & (DH - 1);
#pragma unroll
        for (int mt = 0; mt < 4; ++mt)
#pragma unroll
            for (int r4 = 0; r4 < 4; ++r4) {
                int gr = row0 + mt * 16 + q * 4 + r4;
                if (gr < M) O[(size_t)gr * DH + col] = f2bf(acc[mt][nt][r4]);
            }
    }
}

// ---- edge stream + aggregate: ONE WAVE = ONE NODE = ONE BLOCK; batch-4 prefetch,
//      mask hoisted out of hot loop ----
__global__ __launch_bounds__(64)
void edge_kernel(const unsigned short* __restrict__ Hsb, const unsigned short* __restrict__ Hdb,
                 const unsigned short* __restrict__ Tb,
                 const float* __restrict__ b1,
                 const int* __restrict__ rs, const int* __restrict__ epack,
                 unsigned int* __restrict__ Sbf, int N) {
    const int n = blockIdx.x;
    const int lane = threadIdx.x;
    const int c = lane * 2;
    floatx2 hdn = unpack_bf2(*(const unsigned*)(Hdb + (size_t)n * DH + c))
                + *(const floatx2*)(b1 + c);
    const int s = rs[n], e = rs[n + 1];
    floatx2 acc = {0.f, 0.f};
    const int cnt = e - s;
    if (cnt > 0) {
        const int nb = (cnt + 3) >> 2;
        intx4 pk = __builtin_nontemporal_load((const intx4*)(epack + s));
        unsigned hu[4], tw[4];
        {
            int p0 = pk.x, p1 = pk.y, p2 = pk.z, p3 = pk.w;
            hu[0] = *(const unsigned*)(Hsb + (size_t)(p0 & 0x3ffff) * DH + c);
            hu[1] = *(const unsigned*)(Hsb + (size_t)(p1 & 0x3ffff) * DH + c);
            hu[2] = *(const unsigned*)(Hsb + (size_t)(p2 & 0x3ffff) * DH + c);
            hu[3] = *(const unsigned*)(Hsb + (size_t)(p3 & 0x3ffff) * DH + c);
            tw[0] = *(const unsigned*)(Tb + (size_t)(((unsigned)p0) >> 18) * DH + c);
            tw[1] = *(const unsigned*)(Tb + (size_t)(((unsigned)p1) >> 18) * DH + c);
            tw[2] = *(const unsigned*)(Tb + (size_t)(((unsigned)p2) >> 18) * DH + c);
            tw[3] = *(const unsigned*)(Tb + (size_t)(((unsigned)p3) >> 18) * DH + c);
        }
        for (int b = 0; b < nb - 1; ++b) {
            const int j = s + b * 4;
            intx4 pkN = __builtin_nontemporal_load((const intx4*)(epack + j + 4));
            unsigned huN[4], twN[4];
            {
                int p0 = pkN.x, p1 = pkN.y, p2 = pkN.z, p3 = pkN.w;
                huN[0] = *(const unsigned*)(Hsb + (size_t)(p0 & 0x3ffff) * DH + c);
                huN[1] = *(const unsigned*)(Hsb + (size_t)(p1 & 0x3ffff) * DH + c);
                huN[2] = *(const unsigned*)(Hsb + (size_t)(p2 & 0x3ffff) * DH + c);
                huN[3] = *(const unsigned*)(Hsb + (size_t)(p3 & 0x3ffff) * DH + c);
                twN[0] = *(const unsigned*)(Tb + (size_t)(((unsigned)p0) >> 18) * DH + c);
                twN[1] = *(const unsigned*)(Tb + (size_t)(((unsigned)p1) >> 18) * DH + c);
                twN[2] = *(const unsigned*)(Tb + (size_t)(((unsigned)p2) >> 18) * DH + c);
                twN[3] = *(const unsigned*)(Tb + (size_t)(((unsigned)p3) >> 18) * DH + c);
            }
#pragma unroll
            for (int i = 0; i < 4; ++i) {
                floatx2 pre = unpack_bf2(hu[i]) + hdn + unpack_bf2(tw[i]);
                floatx2 sg;
                sg.x = __builtin_amdgcn_rcpf(1.f + __expf(-pre.x));
                sg.y = __builtin_amdgcn_rcpf(1.f + __expf(-pre.y));
                acc += pre * sg;
            }
#pragma unroll
            for (int i = 0; i < 4; ++i) { hu[i] = huN[i]; tw[i] = twN[i]; }
        }
        {
            const int j = s + (nb - 1) * 4;
#pragma unroll
            for (int i = 0; i < 4; ++i) {
                floatx2 pre = unpack_bf2(hu[i]) + hdn + unpack_bf2(tw[i]);
                floatx2 sg;
                sg.x = __builtin_amdgcn_rcpf(1.f + __expf(-pre.x));
                sg.y = __builtin_amdgcn_rcpf(1.f + __expf(-pre.y));
                float msk = (j + i < e) ? 1.f : 0.f;
                acc += (pre * sg) * msk;
            }
        }
    }
    unsigned lo = f2bf(acc.x), hi = f2bf(acc.y);
    Sbf[(size_t)n * 64 + lane] = lo | (hi << 16);
}

// ---- node update + fused next-layer projection; 32-row tiles ----
template<int LAST>
__global__ __launch_bounds__(256)
void upd_kernel(unsigned short* hbf,
                const unsigned short* __restrict__ Sbf16,
                float* h,
                const unsigned short* __restrict__ PB1T,
                const float* __restrict__ b1v,
                const float* __restrict__ cvec,
                const float* __restrict__ cntf,
                const unsigned short* __restrict__ P2T,
                const float* __restrict__ b2v,
                const float* __restrict__ g, const float* __restrict__ bb,
                const unsigned short* __restrict__ BT,
                unsigned short* __restrict__ O1b, unsigned short* __restrict__ O2b,
                float* __restrict__ O1f, float* __restrict__ O2f,
                int M) {
    __shared__ unsigned short HID[32 * 136];
    __shared__ float red[4][32][2];
    __shared__ float stats[32][2];
    __shared__ float cntL[32];
    const int tid = threadIdx.x;
    const int w = tid >> 6, lane = tid & 63;
    const int mr = lane & 15, q = lane >> 4;
    const int row0 = blockIdx.x * 32;

    if (tid < 32) {
        int r = row0 + tid;
        cntL[tid] = (r < M) ? cntf[r] : 0.f;
    }
    __syncthreads();

    floatx4 acc[2][2] = {};
#pragma unroll
    for (int kc = 0; kc < 8; ++kc) {
        const int ko = kc * 32 + q * 8;
        shortx8 a[2], bfr[2];
#pragma unroll
        for (int mt = 0; mt < 2; ++mt) {
            int r = row0 + mt * 16 + mr; if (r >= M) r = M - 1;
            const unsigned short* sp = (ko < DH) ? (hbf + (size_t)r * DH + ko)
                                                 : (Sbf16 + (size_t)r * DH + (ko - DH));
            a[mt] = *reinterpret_cast<const shortx8*>(sp);
        }
#pragma unroll
        for (int nt = 0; nt < 2; ++nt)
            bfr[nt] = *reinterpret_cast<const shortx8*>(PB1T + (size_t)(w * 32 + nt * 16 + mr) * 256 + ko);
#pragma unroll
        for (int mt = 0; mt < 2; ++mt)
#pragma unroll
            for (int nt = 0; nt < 2; ++nt)
                acc[mt][nt] = __builtin_amdgcn_mfma_f32_16x16x32_bf16(a[mt], bfr[nt], acc[mt][nt], 0, 0, 0);
    }
#pragma unroll
    for (int nt = 0; nt < 2; ++nt) {
        int col = w * 32 + nt * 16 + mr;
        float bv = b1v[col], cv = cvec[col];
#pragma unroll
        for (int mt = 0; mt < 2; ++mt)
#pragma unroll
            for (int r4 = 0; r4 < 4; ++r4) {
                int row = mt * 16 + q * 4 + r4;
                HID[row * 136 + col] = f2bf(fast_silu(acc[mt][nt][r4] + bv + cntL[row] * cv));
            }
    }
    __syncthreads();

    floatx4 acc3[2][2] = {};
#pragma unroll
    for (int kc = 0; kc < 4; ++kc) {
        const int ko = kc * 32 + q * 8;
        shortx8 a[2], bfr[2];
#pragma unroll
        for (int mt = 0; mt < 2; ++mt)
            a[mt] = *reinterpret_cast<const shortx8*>(HID + (mt * 16 + mr) * 136 + ko);
#pragma unroll
        for (int nt = 0; nt < 2; ++nt)
            bfr[nt] = *reinterpret_cast<const shortx8*>(P2T + (size_t)(w * 32 + nt * 16 + mr) * DH + ko);
#pragma unroll
        for (int mt = 0; mt < 2; ++mt)
#pragma unroll
            for (int nt = 0; nt < 2; ++nt)
                acc3[mt][nt] = __builtin_amdgcn_mfma_f32_16x16x32_bf16(a[mt], bfr[nt], acc3[mt][nt], 0, 0, 0);
    }
#pragma unroll
    for (int nt = 0; nt < 2; ++nt) {
        int col = w * 32 + nt * 16 + mr;
        float b2c = b2v[col];
#pragma unroll
        for (int mt = 0; mt < 2; ++mt)
#pragma unroll
            for (int r4 = 0; r4 < 4; ++r4) {
                int gr = row0 + mt * 16 + q * 4 + r4;
                float hv = (gr < M) ? h[(size_t)gr * DH + col] : 0.f;
                acc3[mt][nt][r4] = acc3[mt][nt][r4] + b2c + hv;
            }
    }
#pragma unroll
    for (int mt = 0; mt < 2; ++mt)
#pragma unroll
        for (int r4 = 0; r4 < 4; ++r4) {
            float y0 = acc3[mt][0][r4], y1 = acc3[mt][1][r4];
            float s1 = y0 + y1, s2 = y0 * y0 + y1 * y1;
#pragma unroll
            for (int m = 1; m < 16; m <<= 1) {
                s1 += __shfl_xor(s1, m);
                s2 += __shfl_xor(s2, m);
            }
            if (mr == 0) {
                int row = mt * 16 + q * 4 + r4;
                red[w][row][0] = s1; red[w][row][1] = s2;
            }
        }
    __syncthreads();
    if (tid < 32) {
        float s1 = red[0][tid][0] + red[1][tid][0] + red[2][tid][0] + red[3][tid][0];
        float s2 = red[0][tid][1] + red[1][tid][1] + red[2][tid][1] + red[3][tid][1];
        float mu = s1 * (1.f / DH);
        float var = s2 * (1.f / DH) - mu * mu;
        stats[tid][0] = mu;
        stats[tid][1] = rsqrtf(var + 1e-5f);
    }
    __syncthreads();
#pragma unroll
    for (int nt = 0; nt < 2; ++nt) {
        int col = w * 32 + nt * 16 + mr;
        float gc = g[col], bc = bb[col];
#pragma unroll
        for (int mt = 0; mt < 2; ++mt)
#pragma unroll
            for (int r4 = 0; r4 < 4; ++r4) {
                int row = mt * 16 + q * 4 + r4;
                int gr = row0 + row;
                if (gr < M) {
                    float yv = (acc3[mt][nt][r4] - stats[row][0]) * stats[row][1] * gc + bc;
                    unsigned short yb = f2bf(yv);
                    h[(size_t)gr * DH + col] = yv;
                    hbf[(size_t)gr * DH + col] = yb;
                    HID[row * 136 + col] = yb;
                }
            }
    }
    __syncthreads();

    floatx4 acc4[2][4] = {};
#pragma unroll
    for (int kc = 0; kc < 4; ++kc) {
        const int ko = kc * 32 + q * 8;
        shortx8 a[2], b[4];
#pragma unroll
        for (int mt = 0; mt < 2; ++mt)
            a[mt] = *reinterpret_cast<const shortx8*>(HID + (mt * 16 + mr) * 136 + ko);
#pragma unroll
        for (int nt = 0; nt < 4; ++nt) {
            int ocol = w * 64 + nt * 16 + mr;
            b[nt] = *reinterpret_cast<const shortx8*>(BT + (size_t)ocol * DH + ko);
        }
#pragma unroll
        for (int mt = 0; mt < 2; ++mt)
#pragma unroll
            for (int nt = 0; nt < 4; ++nt)
                acc4[mt][nt] = __builtin_amdgcn_mfma_f32_16x16x32_bf16(a[mt], b[nt], acc4[mt][nt], 0, 0, 0);
    }
#pragma unroll
    for (int nt = 0; nt < 4; ++nt) {
        int ocol = w * 64 + nt * 16 + mr;
        int col = ocol & (DH - 1);
#pragma unroll
        for (int mt = 0; mt < 2; ++mt)
#pragma unroll
            for (int r4 = 0; r4 < 4; ++r4) {
                int gr = row0 + mt * 16 + q * 4 + r4;
                if (gr < M) {
                    if (LAST) {
                        float* O = (ocol < DH) ? O1f : O2f;
                        O[(size_t)gr * DH + col] = acc4[mt][nt][r4];
                    } else {
                        unsigned short* O = (ocol < DH) ? O1b : O2b;
                        O[(size_t)gr * DH + col] = f2bf(acc4[mt][nt][r4]);
                    }
                }
            }
    }
}

// ---- pair head: 4 pairs per wave (16-lane groups, 8 channels/lane via 2x float4) ----
__global__ __launch_bounds__(256)
void pair_kernel(const float* __restrict__ Hu, const float* __restrict__ Hv,
                 const int* __restrict__ pairs, const float* __restrict__ xyr,
                 const float* __restrict__ ehw1c,
                 const float* __restrict__ eb1, const float* __restrict__ ew2,
                 const float* __restrict__ eb2,
                 float* __restrict__ out, int P) {
    int grp = threadIdx.x >> 4;                  // 0..15 per block
    int p = blockIdx.x * 16 + grp;
    bool valid = (p < P);
    int pp = valid ? p : (P - 1);
    int u = pairs[2 * pp], v = pairs[2 * pp + 1];
    float ru = xyr[3 * u + 2], rv_ = xyr[3 * v + 2];
    float dx = xyr[3 * u] - xyr[3 * v];
    float dy = xyr[3 * u + 1] - xyr[3 * v + 1];
    float dist = sqrtf(dx * dx + dy * dy + 1e-8f);
    float adr = fabsf(ru - rv_);
    int c = (threadIdx.x & 15) * 8;
    float val = 0.f;
#pragma unroll
    for (int hf = 0; hf < 2; ++hf) {
        int cc = c + hf * 4;
        floatx4 hu4 = *(const floatx4*)(Hu + (size_t)u * DH + cc);
        floatx4 hv4 = *(const floatx4*)(Hv + (size_t)v * DH + cc);
        floatx4 bv = *(const floatx4*)(eb1 + cc);
        floatx4 wv = *(const floatx4*)(ew2 + cc);
        floatx4 c0 = *(const floatx4*)(ehw1c + 0 * DH + cc);
        floatx4 c1 = *(const floatx4*)(ehw1c + 1 * DH + cc);
        floatx4 c2 = *(const floatx4*)(ehw1c + 2 * DH + cc);
        floatx4 c3 = *(const floatx4*)(ehw1c + 3 * DH + cc);
        floatx4 px = hu4 + hv4 + bv + ru * c0 + rv_ * c1 + dist * c2 + adr * c3;
        val += fast_silu(px.x) * wv.x + fast_silu(px.y) * wv.y +
               fast_silu(px.z) * wv.z + fast_silu(px.w) * wv.w;
    }
#pragma unroll
    for (int m = 1; m < 16; m <<= 1) val += __shfl_xor(val, m);
    if (((threadIdx.x & 15) == 0) && valid) out[p] = val + eb2[0];
}

extern "C" void kernel_launch(void* const* d_in, const int* in_sizes, int n_in,
                              void* d_out, int out_size, void* d_ws, size_t ws_size,
                              hipStream_t stream) {
    const float* xyr     = (const float*)d_in[0];
    const int*   eidx    = (const int*)d_in[1];
    const int*   pairs   = (const int*)d_in[2];
    const float* node_w1 = (const float*)d_in[3];
    const float* node_b1 = (const float*)d_in[4];
    const float* node_w2 = (const float*)d_in[5];
    const float* node_b2 = (const float*)d_in[6];
    const float* pm_w1   = (const float*)d_in[7];
    const float* pm_b1   = (const float*)d_in[8];
    const float* pm_w2   = (const float*)d_in[9];
    const float* pm_b2   = (const float*)d_in[10];
    const float* ph_w1   = (const float*)d_in[11];
    const float* ph_b1   = (const float*)d_in[12];
    const float* ph_w2   = (const float*)d_in[13];
    const float* ph_b2   = (const float*)d_in[14];
    const float* ln_g    = (const float*)d_in[15];
    const float* ln_b    = (const float*)d_in[16];
    const float* eh_w1   = (const float*)d_in[17];
    const float* eh_b1   = (const float*)d_in[18];
    const float* eh_w2   = (const float*)d_in[19];
    const float* eh_b2   = (const float*)d_in[20];

    const int N = in_sizes[0] / 3;
    const int E = in_sizes[1] / 2;
    const int P = in_sizes[2] / 2;
    const int* src = eidx;
    const int* dst = eidx + E;

    char* ws = (char*)d_ws;
    size_t off = 0;
    auto alloc = [&](size_t bytes) -> char* {
        char* p = ws + off;
        off += (bytes + 255) & ~(size_t)255;
        return p;
    };
    unsigned short* W1abT = (unsigned short*)alloc((size_t)3 * 256 * 128 * 2);
    unsigned short* PB1T  = (unsigned short*)alloc((size_t)3 * 128 * 256 * 2);
    unsigned short* PH2T  = (unsigned short*)alloc((size_t)3 * 128 * 128 * 2);
    unsigned short* EHT   = (unsigned short*)alloc((size_t)256 * 128 * 2);
    float*          cvec  = (float*)alloc((size_t)3 * 128 * 4);
    unsigned short* Ttab  = (unsigned short*)alloc((size_t)3 * (TGRID + 1) * 128 * 2);
    float*          h     = (float*)alloc((size_t)N * DH * 4);
    unsigned short* hbf   = (unsigned short*)alloc((size_t)N * DH * 2);
    unsigned short* Hsb   = (unsigned short*)alloc((size_t)N * DH * 2);
    unsigned short* Hdb   = (unsigned short*)alloc((size_t)N * DH * 2);
    float*          Hs    = (float*)alloc((size_t)N * DH * 4);
    float*          Hd    = (float*)alloc((size_t)N * DH * 4);
    unsigned int*   Sbf   = (unsigned int*)alloc((size_t)N * 64 * 4);
    int*            epack = (int*)alloc((size_t)(E + 32) * 4);
    int*            cnt   = (int*)alloc((size_t)N * 4);
    int*            rs    = (int*)alloc((size_t)(N + 1) * 4);
    int*            cursor= (int*)alloc((size_t)N * 4);
    float*          cntf  = (float*)alloc((size_t)N * 4);
    (void)ws_size; (void)n_in; (void)out_size;

    const int PREP_TOT = 3 * 256 * 128 + 256 * 128 + 3 * 128 * 256 + 3 * 128 * 128
                       + 3 * 128 + 3 * (TGRID + 1) * 128 + N;
    const int PB = (PREP_TOT + 255) / 256;
    const int NODEB = (N + 31) / 32;
    prep_all_kernel<<<PB + NODEB, 256, 0, stream>>>(pm_w1, eh_w1, ph_w1, ph_w2,
                                                    pm_w2, pm_b2,
                                                    W1abT, EHT, PB1T, PH2T,
                                                    cvec, Ttab, cnt,
                                                    xyr, node_w1, node_b1, node_w2, node_b2,
                                                    h, hbf, N, PB);

    count_kernel<<<(E + 255) / 256, 256, 0, stream>>>(dst, cnt, E);
    scan_kernel<<<1, 1024, 0, stream>>>(cnt, rs, cursor, cntf, N);
    fill_kernel<<<(E + 255) / 256, 256, 0, stream>>>(src, dst, cursor, xyr, epack, E);

    const int MB  = (N + 63) / 64;
    const int MB2 = (N + 31) / 32;
    proj_kernel<<<MB, 256, 0, stream>>>(hbf, W1abT, Hsb, Hdb, N);
    for (int l = 0; l < 3; ++l) {
        edge_kernel<<<N, 64, 0, stream>>>(Hsb, Hdb, Ttab + (size_t)l * (TGRID + 1) * 128,
                                          pm_b1 + l * DH, rs, epack, Sbf, N);
        if (l < 2) {
            upd_kernel<0><<<MB2, 256, 0, stream>>>(hbf, (const unsigned short*)Sbf, h,
                                                   PB1T + (size_t)l * 128 * 256, ph_b1 + l * DH,
                                                   cvec + l * 128, cntf,
                                                   PH2T + (size_t)l * 128 * 128, ph_b2 + l * DH,
                                                   ln_g + l * DH, ln_b + l * DH,
                                                   W1abT + (size_t)(l + 1) * 256 * 128,
                                                   Hsb, Hdb, nullptr, nullptr, N);
        } else {
            upd_kernel<1><<<MB2, 256, 0, stream>>>(hbf, (const unsigned short*)Sbf, h,
                                                   PB1T + (size_t)l * 128 * 256, ph_b1 + l * DH,
                                                   cvec + l * 128, cntf,
                                                   PH2T + (size_t)l * 128 * 128, ph_b2 + l * DH,
                                                   ln_g + l * DH, ln_b + l * DH,
                                                   EHT, nullptr, nullptr, Hs, Hd, N);
        }
    }

    pair_kernel<<<(P + 15) / 16, 256, 0, stream>>>(Hs, Hd, pairs, xyr, eh_w1 + 256 * DH,
                                                   eh_b1, eh_w2, eh_b2, (float*)d_out, P);
}

// Round 17
// 327.688 us; speedup vs baseline: 1.0466x; 1.0053x over previous
//
#include <hip/hip_runtime.h>

#define DH 128
#define RMAXF 1.41421356237309515f
#define TGRID 2048

typedef float  floatx4 __attribute__((ext_vector_type(4)));
typedef float  floatx2 __attribute__((ext_vector_type(2)));
typedef short  shortx8 __attribute__((ext_vector_type(8)));
typedef int    intx4  __attribute__((ext_vector_type(4)));

__device__ __forceinline__ unsigned short f2bf(float f) {
    unsigned u = __builtin_bit_cast(unsigned, f);
    u += 0x7fffu + ((u >> 16) & 1u);
    return (unsigned short)(u >> 16);
}
__device__ __forceinline__ floatx2 unpack_bf2(unsigned u) {
    floatx2 r;
    r.x = __builtin_bit_cast(float, u << 16);
    r.y = __builtin_bit_cast(float, u & 0xffff0000u);
    return r;
}
__device__ __forceinline__ float fast_silu(float x) {
    return x * __builtin_amdgcn_rcpf(1.f + __expf(-x));
}

// ---- one prep kernel: bf16 transposed weights (W2P/cvec dots inline), bf16 NN RBF table,
//      node-encoder tail blocks, PLUS degree-count tail blocks (cnt pre-zeroed by memset) ----
__global__ __launch_bounds__(256)
void prep_all_kernel(const float* __restrict__ pm_w1, const float* __restrict__ eh_w1,
                     const float* __restrict__ ph_w1, const float* __restrict__ ph_w2,
                     const float* __restrict__ pm_w2, const float* __restrict__ pm_b2,
                     unsigned short* __restrict__ W1abT, unsigned short* __restrict__ EHT,
                     unsigned short* __restrict__ PB1T, unsigned short* __restrict__ PH2T,
                     float* __restrict__ cvec, unsigned short* __restrict__ Tb,
                     int* __restrict__ cnt, const int* __restrict__ dst, int E,
                     const float* __restrict__ xyr,
                     const float* __restrict__ nw1, const float* __restrict__ nb1,
                     const float* __restrict__ nw2, const float* __restrict__ nb2,
                     float* __restrict__ h, unsigned short* __restrict__ hbf,
                     int N, int PB, int NODEB) {
    if ((int)blockIdx.x >= PB + NODEB) {
        // ---- degree count tail: atomicAdd into pre-zeroed cnt ----
        int e = ((int)blockIdx.x - PB - NODEB) * 256 + threadIdx.x;
        if (e < E) atomicAdd(&cnt[dst[e]], 1);
        return;
    }
    if ((int)blockIdx.x >= PB) {
        __shared__ float xs[32][3];
        __shared__ float hid[32][DH];
        const int g = threadIdx.x >> 7;
        const int t = threadIdx.x & 127;
        const int n0 = ((int)blockIdx.x - PB) * 32 + g * 16;
        if (t < 48) {
            int i = t / 3, j = t - 3 * (t / 3);
            int n = n0 + i; if (n >= N) n = N - 1;
            xs[g * 16 + i][j] = xyr[3 * n + j];
        }
        __syncthreads();
        int col = t;
        float w10 = nw1[col], w11 = nw1[DH + col], w12 = nw1[2 * DH + col];
        float bb = nb1[col];
#pragma unroll
        for (int i = 0; i < 16; ++i) {
            float v = bb + xs[g * 16 + i][0] * w10 + xs[g * 16 + i][1] * w11 + xs[g * 16 + i][2] * w12;
            hid[g * 16 + i][col] = fast_silu(v);
        }
        __syncthreads();
        float a[16];
#pragma unroll
        for (int i = 0; i < 16; ++i) a[i] = nb2[col];
        for (int j = 0; j < DH; ++j) {
            float wv = nw2[j * DH + col];
#pragma unroll
            for (int i = 0; i < 16; ++i) a[i] += hid[g * 16 + i][j] * wv;
        }
        for (int i = 0; i < 16; ++i) {
            int n = n0 + i;
            if (n < N) {
                h[(size_t)n * DH + col] = a[i];
                hbf[(size_t)n * DH + col] = f2bf(a[i]);
            }
        }
        return;
    }
    int idx = blockIdx.x * 256 + threadIdx.x;
    const int nA = 3 * 256 * 128;
    const int nB = 256 * 128;
    const int nC = 3 * 128 * 256;
    const int nD = 3 * 128 * 128;
    const int nE = 3 * 128;
    const int nT = 3 * (TGRID + 1) * 128;
    if (idx < nA) {
        int l = idx / (256 * 128);
        int rem = idx - l * 256 * 128;
        int j = rem >> 7, k = rem & 127;
        int srow = ((j >> 7) << 7) + k;
        W1abT[idx] = f2bf(pm_w1[(size_t)l * 272 * 128 + (size_t)srow * 128 + (j & 127)]);
        return;
    }
    idx -= nA;
    if (idx < nB) {
        int j = idx >> 7, k = idx & 127;
        int srow = ((j >> 7) << 7) + k;
        EHT[idx] = f2bf(eh_w1[(size_t)srow * 128 + (j & 127)]);
        return;
    }
    idx -= nB;
    if (idx < nC) {
        int l = idx / (128 * 256);
        int rem = idx - l * 128 * 256;
        int j = rem >> 8, k = rem & 255;
        float v;
        if (k < 128) {
            v = ph_w1[(size_t)l * 256 * 128 + (size_t)k * 128 + j];
        } else {
            const float* w2r = pm_w2 + (size_t)l * 128 * 128 + (size_t)(k - 128) * 128;
            const float* p1b = ph_w1 + (size_t)l * 256 * 128 + (size_t)128 * 128 + j;
            float s = 0.f;
            for (int m = 0; m < 128; ++m) s += w2r[m] * p1b[(size_t)m * 128];
            v = s;
        }
        PB1T[idx] = f2bf(v);
        return;
    }
    idx -= nC;
    if (idx < nD) {
        int l = idx / (128 * 128);
        int rem = idx - l * 128 * 128;
        int j = rem >> 7, k = rem & 127;
        PH2T[idx] = f2bf(ph_w2[(size_t)l * 128 * 128 + (size_t)k * 128 + j]);
        return;
    }
    idx -= nD;
    if (idx < nE) {
        int l = idx >> 7, o = idx & 127;
        const float* b2 = pm_b2 + l * 128;
        const float* p1b = ph_w1 + (size_t)l * 256 * 128 + (size_t)128 * 128 + o;
        float s = 0.f;
        for (int m = 0; m < 128; ++m) s += b2[m] * p1b[(size_t)m * 128];
        cvec[idx] = s;
        return;
    }
    idx -= nE;
    if (idx < nT) {
        int l = idx / ((TGRID + 1) * 128);
        int rem = idx - l * (TGRID + 1) * 128;
        int i = rem >> 7, ch = rem & 127;
        float r = (float)i * (RMAXF / (float)TGRID);
        const float step = RMAXF / 15.f;
        const float gamma = 56.25f;
        const float* w1c = pm_w1 + (size_t)l * 272 * 128 + (size_t)256 * 128 + ch;
        float s = 0.f;
#pragma unroll
        for (int k = 0; k < 16; ++k) {
            float d = r - (float)k * step;
            s += expf(-gamma * d * d) * w1c[(size_t)k * 128];
        }
        Tb[idx] = f2bf(s);
    }
}

// ---- CSR scan ----
__global__ __launch_bounds__(1024)
void scan_kernel(const int* __restrict__ cnt, int* __restrict__ rs, int* __restrict__ cursor,
                 float* __restrict__ cntf, int N) {
    __shared__ int ps[1024];
    const int CH = 16;
    int t = threadIdx.x;
    int base = t * CH;
    int loc[CH];
    int s = 0;
#pragma unroll
    for (int j = 0; j < CH; ++j) {
        int i = base + j;
        int v = (i < N) ? cnt[i] : 0;
        if (i < N) cntf[i] = (float)v;
        loc[j] = s; s += v;
    }
    ps[t] = s;
    __syncthreads();
    for (int off = 1; off < 1024; off <<= 1) {
        int v = (t >= off) ? ps[t - off] : 0;
        __syncthreads();
        ps[t] += v;
        __syncthreads();
    }
    int pre = (t > 0) ? ps[t - 1] : 0;
#pragma unroll
    for (int j = 0; j < CH; ++j) {
        int i = base + j;
        if (i < N) { int v = pre + loc[j]; rs[i] = v; cursor[i] = v; }
    }
    if (t == 0) rs[N] = ps[1023];
}
// ---- fill: per CSR slot store packed {src | T-row-index<<18}; pads 32 tail slots ----
__global__ void fill_kernel(const int* __restrict__ src, const int* __restrict__ dst,
                            int* __restrict__ cursor, const float* __restrict__ xyr,
                            int* __restrict__ epack, int E) {
    int e = blockIdx.x * 256 + threadIdx.x;
    if (e < 32) epack[E + e] = 0;
    if (e >= E) return;
    int s = src[e], d = dst[e];
    int p = atomicAdd(&cursor[d], 1);
    float dx = xyr[3 * s] - xyr[3 * d];
    float dy = xyr[3 * s + 1] - xyr[3 * d + 1];
    float r = sqrtf(dx * dx + dy * dy + 1e-8f);
    int ti = (int)(r * ((float)TGRID / RMAXF) + 0.5f);
    ti = (ti > TGRID) ? TGRID : ti;
    epack[p] = s | (ti << 18);
}

// ---- proj (layer-0): Hsb||Hdb (bf16) = hbf @ W1abT^T ----
__global__ __launch_bounds__(256)
void proj_kernel(const unsigned short* __restrict__ Abf,
                 const unsigned short* __restrict__ BT,
                 unsigned short* __restrict__ O1b, unsigned short* __restrict__ O2b, int M) {
    const int tid = threadIdx.x;
    const int w = tid >> 6, lane = tid & 63;
    const int mr = lane & 15, q = lane >> 4;
    const int row0 = blockIdx.x * 64;
    floatx4 acc[4][4] = {};
#pragma unroll
    for (int kc = 0; kc < 4; ++kc) {
        const int ko = kc * 32 + q * 8;
        shortx8 a[4], b[4];
#pragma unroll
        for (int mt = 0; mt < 4; ++mt) {
            int r = row0 + mt * 16 + mr; if (r >= M) r = M - 1;
            a[mt] = *reinterpret_cast<const shortx8*>(Abf + (size_t)r * DH + ko);
        }
#pragma unroll
        for (int nt = 0; nt < 4; ++nt) {
            int ocol = w * 64 + nt * 16 + mr;
            b[nt] = *reinterpret_cast<const shortx8*>(BT + (size_t)ocol * DH + ko);
        }
#pragma unroll
        for (int mt = 0; mt < 4; ++mt)
#pragma unroll
            for (int nt = 0; nt < 4; ++nt)
                acc[mt][nt] = __builtin_amdgcn_mfma_f32_16x16x32_bf16(a[mt], b[nt], acc[mt][nt], 0, 0, 0);
    }
#pragma unroll
    for (int nt = 0; nt < 4; ++nt) {
        int ocol = w * 64 + nt * 16 + mr;
        unsigned short* O = (ocol < DH) ? O1b : O2b;
        int col = ocol & (DH - 1);
#pragma unroll
        for (int mt = 0; mt < 4; ++mt)
#pragma unroll
            for (int r4 = 0; r4 < 4; ++r4) {
                int gr = row0 + mt * 16 + q * 4 + r4;
                if (gr < M) O[(size_t)gr * DH + col] = f2bf(acc[mt][nt][r4]);
            }
    }
}

// ---- edge stream + aggregate: ONE WAVE = ONE NODE = ONE BLOCK; batch-4 prefetch,
//      mask hoisted out of hot loop ----
__global__ __launch_bounds__(64)
void edge_kernel(const unsigned short* __restrict__ Hsb, const unsigned short* __restrict__ Hdb,
                 const unsigned short* __restrict__ Tb,
                 const float* __restrict__ b1,
                 const int* __restrict__ rs, const int* __restrict__ epack,
                 unsigned int* __restrict__ Sbf, int N) {
    const int n = blockIdx.x;
    const int lane = threadIdx.x;
    const int c = lane * 2;
    floatx2 hdn = unpack_bf2(*(const unsigned*)(Hdb + (size_t)n * DH + c))
                + *(const floatx2*)(b1 + c);
    const int s = rs[n], e = rs[n + 1];
    floatx2 acc = {0.f, 0.f};
    const int cnt = e - s;
    if (cnt > 0) {
        const int nb = (cnt + 3) >> 2;
        intx4 pk = __builtin_nontemporal_load((const intx4*)(epack + s));
        unsigned hu[4], tw[4];
        {
            int p0 = pk.x, p1 = pk.y, p2 = pk.z, p3 = pk.w;
            hu[0] = *(const unsigned*)(Hsb + (size_t)(p0 & 0x3ffff) * DH + c);
            hu[1] = *(const unsigned*)(Hsb + (size_t)(p1 & 0x3ffff) * DH + c);
            hu[2] = *(const unsigned*)(Hsb + (size_t)(p2 & 0x3ffff) * DH + c);
            hu[3] = *(const unsigned*)(Hsb + (size_t)(p3 & 0x3ffff) * DH + c);
            tw[0] = *(const unsigned*)(Tb + (size_t)(((unsigned)p0) >> 18) * DH + c);
            tw[1] = *(const unsigned*)(Tb + (size_t)(((unsigned)p1) >> 18) * DH + c);
            tw[2] = *(const unsigned*)(Tb + (size_t)(((unsigned)p2) >> 18) * DH + c);
            tw[3] = *(const unsigned*)(Tb + (size_t)(((unsigned)p3) >> 18) * DH + c);
        }
        for (int b = 0; b < nb - 1; ++b) {
            const int j = s + b * 4;
            intx4 pkN = __builtin_nontemporal_load((const intx4*)(epack + j + 4));
            unsigned huN[4], twN[4];
            {
                int p0 = pkN.x, p1 = pkN.y, p2 = pkN.z, p3 = pkN.w;
                huN[0] = *(const unsigned*)(Hsb + (size_t)(p0 & 0x3ffff) * DH + c);
                huN[1] = *(const unsigned*)(Hsb + (size_t)(p1 & 0x3ffff) * DH + c);
                huN[2] = *(const unsigned*)(Hsb + (size_t)(p2 & 0x3ffff) * DH + c);
                huN[3] = *(const unsigned*)(Hsb + (size_t)(p3 & 0x3ffff) * DH + c);
                twN[0] = *(const unsigned*)(Tb + (size_t)(((unsigned)p0) >> 18) * DH + c);
                twN[1] = *(const unsigned*)(Tb + (size_t)(((unsigned)p1) >> 18) * DH + c);
                twN[2] = *(const unsigned*)(Tb + (size_t)(((unsigned)p2) >> 18) * DH + c);
                twN[3] = *(const unsigned*)(Tb + (size_t)(((unsigned)p3) >> 18) * DH + c);
            }
#pragma unroll
            for (int i = 0; i < 4; ++i) {
                floatx2 pre = unpack_bf2(hu[i]) + hdn + unpack_bf2(tw[i]);
                floatx2 sg;
                sg.x = __builtin_amdgcn_rcpf(1.f + __expf(-pre.x));
                sg.y = __builtin_amdgcn_rcpf(1.f + __expf(-pre.y));
                acc += pre * sg;
            }
#pragma unroll
            for (int i = 0; i < 4; ++i) { hu[i] = huN[i]; tw[i] = twN[i]; }
        }
        {
            const int j = s + (nb - 1) * 4;
#pragma unroll
            for (int i = 0; i < 4; ++i) {
                floatx2 pre = unpack_bf2(hu[i]) + hdn + unpack_bf2(tw[i]);
                floatx2 sg;
                sg.x = __builtin_amdgcn_rcpf(1.f + __expf(-pre.x));
                sg.y = __builtin_amdgcn_rcpf(1.f + __expf(-pre.y));
                float msk = (j + i < e) ? 1.f : 0.f;
                acc += (pre * sg) * msk;
            }
        }
    }
    unsigned lo = f2bf(acc.x), hi = f2bf(acc.y);
    Sbf[(size_t)n * 64 + lane] = lo | (hi << 16);
}

// ---- node update + fused next-layer projection; 32-row tiles ----
template<int LAST>
__global__ __launch_bounds__(256)
void upd_kernel(unsigned short* hbf,
                const unsigned short* __restrict__ Sbf16,
                float* h,
                const unsigned short* __restrict__ PB1T,
                const float* __restrict__ b1v,
                const float* __restrict__ cvec,
                const float* __restrict__ cntf,
                const unsigned short* __restrict__ P2T,
                const float* __restrict__ b2v,
                const float* __restrict__ g, const float* __restrict__ bb,
                const unsigned short* __restrict__ BT,
                unsigned short* __restrict__ O1b, unsigned short* __restrict__ O2b,
                float* __restrict__ O1f, float* __restrict__ O2f,
                int M) {
    __shared__ unsigned short HID[32 * 136];
    __shared__ float red[4][32][2];
    __shared__ float stats[32][2];
    __shared__ float cntL[32];
    const int tid = threadIdx.x;
    const int w = tid >> 6, lane = tid & 63;
    const int mr = lane & 15, q = lane >> 4;
    const int row0 = blockIdx.x * 32;

    if (tid < 32) {
        int r = row0 + tid;
        cntL[tid] = (r < M) ? cntf[r] : 0.f;
    }
    __syncthreads();

    floatx4 acc[2][2] = {};
#pragma unroll
    for (int kc = 0; kc < 8; ++kc) {
        const int ko = kc * 32 + q * 8;
        shortx8 a[2], bfr[2];
#pragma unroll
        for (int mt = 0; mt < 2; ++mt) {
            int r = row0 + mt * 16 + mr; if (r >= M) r = M - 1;
            const unsigned short* sp = (ko < DH) ? (hbf + (size_t)r * DH + ko)
                                                 : (Sbf16 + (size_t)r * DH + (ko - DH));
            a[mt] = *reinterpret_cast<const shortx8*>(sp);
        }
#pragma unroll
        for (int nt = 0; nt < 2; ++nt)
            bfr[nt] = *reinterpret_cast<const shortx8*>(PB1T + (size_t)(w * 32 + nt * 16 + mr) * 256 + ko);
#pragma unroll
        for (int mt = 0; mt < 2; ++mt)
#pragma unroll
            for (int nt = 0; nt < 2; ++nt)
                acc[mt][nt] = __builtin_amdgcn_mfma_f32_16x16x32_bf16(a[mt], bfr[nt], acc[mt][nt], 0, 0, 0);
    }
#pragma unroll
    for (int nt = 0; nt < 2; ++nt) {
        int col = w * 32 + nt * 16 + mr;
        float bv = b1v[col], cv = cvec[col];
#pragma unroll
        for (int mt = 0; mt < 2; ++mt)
#pragma unroll
            for (int r4 = 0; r4 < 4; ++r4) {
                int row = mt * 16 + q * 4 + r4;
                HID[row * 136 + col] = f2bf(fast_silu(acc[mt][nt][r4] + bv + cntL[row] * cv));
            }
    }
    __syncthreads();

    floatx4 acc3[2][2] = {};
#pragma unroll
    for (int kc = 0; kc < 4; ++kc) {
        const int ko = kc * 32 + q * 8;
        shortx8 a[2], bfr[2];
#pragma unroll
        for (int mt = 0; mt < 2; ++mt)
            a[mt] = *reinterpret_cast<const shortx8*>(HID + (mt * 16 + mr) * 136 + ko);
#pragma unroll
        for (int nt = 0; nt < 2; ++nt)
            bfr[nt] = *reinterpret_cast<const shortx8*>(P2T + (size_t)(w * 32 + nt * 16 + mr) * DH + ko);
#pragma unroll
        for (int mt = 0; mt < 2; ++mt)
#pragma unroll
            for (int nt = 0; nt < 2; ++nt)
                acc3[mt][nt] = __builtin_amdgcn_mfma_f32_16x16x32_bf16(a[mt], bfr[nt], acc3[mt][nt], 0, 0, 0);
    }
#pragma unroll
    for (int nt = 0; nt < 2; ++nt) {
        int col = w * 32 + nt * 16 + mr;
        float b2c = b2v[col];
#pragma unroll
        for (int mt = 0; mt < 2; ++mt)
#pragma unroll
            for (int r4 = 0; r4 < 4; ++r4) {
                int gr = row0 + mt * 16 + q * 4 + r4;
                float hv = (gr < M) ? h[(size_t)gr * DH + col] : 0.f;
                acc3[mt][nt][r4] = acc3[mt][nt][r4] + b2c + hv;
            }
    }
#pragma unroll
    for (int mt = 0; mt < 2; ++mt)
#pragma unroll
        for (int r4 = 0; r4 < 4; ++r4) {
            float y0 = acc3[mt][0][r4], y1 = acc3[mt][1][r4];
            float s1 = y0 + y1, s2 = y0 * y0 + y1 * y1;
#pragma unroll
            for (int m = 1; m < 16; m <<= 1) {
                s1 += __shfl_xor(s1, m);
                s2 += __shfl_xor(s2, m);
            }
            if (mr == 0) {
                int row = mt * 16 + q * 4 + r4;
                red[w][row][0] = s1; red[w][row][1] = s2;
            }
        }
    __syncthreads();
    if (tid < 32) {
        float s1 = red[0][tid][0] + red[1][tid][0] + red[2][tid][0] + red[3][tid][0];
        float s2 = red[0][tid][1] + red[1][tid][1] + red[2][tid][1] + red[3][tid][1];
        float mu = s1 * (1.f / DH);
        float var = s2 * (1.f / DH) - mu * mu;
        stats[tid][0] = mu;
        stats[tid][1] = rsqrtf(var + 1e-5f);
    }
    __syncthreads();
#pragma unroll
    for (int nt = 0; nt < 2; ++nt) {
        int col = w * 32 + nt * 16 + mr;
        float gc = g[col], bc = bb[col];
#pragma unroll
        for (int mt = 0; mt < 2; ++mt)
#pragma unroll
            for (int r4 = 0; r4 < 4; ++r4) {
                int row = mt * 16 + q * 4 + r4;
                int gr = row0 + row;
                if (gr < M) {
                    float yv = (acc3[mt][nt][r4] - stats[row][0]) * stats[row][1] * gc + bc;
                    unsigned short yb = f2bf(yv);
                    h[(size_t)gr * DH + col] = yv;
                    hbf[(size_t)gr * DH + col] = yb;
                    HID[row * 136 + col] = yb;
                }
            }
    }
    __syncthreads();

    floatx4 acc4[2][4] = {};
#pragma unroll
    for (int kc = 0; kc < 4; ++kc) {
        const int ko = kc * 32 + q * 8;
        shortx8 a[2], b[4];
#pragma unroll
        for (int mt = 0; mt < 2; ++mt)
            a[mt] = *reinterpret_cast<const shortx8*>(HID + (mt * 16 + mr) * 136 + ko);
#pragma unroll
        for (int nt = 0; nt < 4; ++nt) {
            int ocol = w * 64 + nt * 16 + mr;
            b[nt] = *reinterpret_cast<const shortx8*>(BT + (size_t)ocol * DH + ko);
        }
#pragma unroll
        for (int mt = 0; mt < 2; ++mt)
#pragma unroll
            for (int nt = 0; nt < 4; ++nt)
                acc4[mt][nt] = __builtin_amdgcn_mfma_f32_16x16x32_bf16(a[mt], b[nt], acc4[mt][nt], 0, 0, 0);
    }
#pragma unroll
    for (int nt = 0; nt < 4; ++nt) {
        int ocol = w * 64 + nt * 16 + mr;
        int col = ocol & (DH - 1);
#pragma unroll
        for (int mt = 0; mt < 2; ++mt)
#pragma unroll
            for (int r4 = 0; r4 < 4; ++r4) {
                int gr = row0 + mt * 16 + q * 4 + r4;
                if (gr < M) {
                    if (LAST) {
                        float* O = (ocol < DH) ? O1f : O2f;
                        O[(size_t)gr * DH + col] = acc4[mt][nt][r4];
                    } else {
                        unsigned short* O = (ocol < DH) ? O1b : O2b;
                        O[(size_t)gr * DH + col] = f2bf(acc4[mt][nt][r4]);
                    }
                }
            }
    }
}

// ---- pair head: 4 pairs per wave (16-lane groups, 8 channels/lane via 2x float4) ----
__global__ __launch_bounds__(256)
void pair_kernel(const float* __restrict__ Hu, const float* __restrict__ Hv,
                 const int* __restrict__ pairs, const float* __restrict__ xyr,
                 const float* __restrict__ ehw1c,
                 const float* __restrict__ eb1, const float* __restrict__ ew2,
                 const float* __restrict__ eb2,
                 float* __restrict__ out, int P) {
    int grp = threadIdx.x >> 4;
    int p = blockIdx.x * 16 + grp;
    bool valid = (p < P);
    int pp = valid ? p : (P - 1);
    int u = pairs[2 * pp], v = pairs[2 * pp + 1];
    float ru = xyr[3 * u + 2], rv_ = xyr[3 * v + 2];
    float dx = xyr[3 * u] - xyr[3 * v];
    float dy = xyr[3 * u + 1] - xyr[3 * v + 1];
    float dist = sqrtf(dx * dx + dy * dy + 1e-8f);
    float adr = fabsf(ru - rv_);
    int c = (threadIdx.x & 15) * 8;
    float val = 0.f;
#pragma unroll
    for (int hf = 0; hf < 2; ++hf) {
        int cc = c + hf * 4;
        floatx4 hu4 = *(const floatx4*)(Hu + (size_t)u * DH + cc);
        floatx4 hv4 = *(const floatx4*)(Hv + (size_t)v * DH + cc);
        floatx4 bv = *(const floatx4*)(eb1 + cc);
        floatx4 wv = *(const floatx4*)(ew2 + cc);
        floatx4 c0 = *(const floatx4*)(ehw1c + 0 * DH + cc);
        floatx4 c1 = *(const floatx4*)(ehw1c + 1 * DH + cc);
        floatx4 c2 = *(const floatx4*)(ehw1c + 2 * DH + cc);
        floatx4 c3 = *(const floatx4*)(ehw1c + 3 * DH + cc);
        floatx4 px = hu4 + hv4 + bv + ru * c0 + rv_ * c1 + dist * c2 + adr * c3;
        val += fast_silu(px.x) * wv.x + fast_silu(px.y) * wv.y +
               fast_silu(px.z) * wv.z + fast_silu(px.w) * wv.w;
    }
#pragma unroll
    for (int m = 1; m < 16; m <<= 1) val += __shfl_xor(val, m);
    if (((threadIdx.x & 15) == 0) && valid) out[p] = val + eb2[0];
}

extern "C" void kernel_launch(void* const* d_in, const int* in_sizes, int n_in,
                              void* d_out, int out_size, void* d_ws, size_t ws_size,
                              hipStream_t stream) {
    const float* xyr     = (const float*)d_in[0];
    const int*   eidx    = (const int*)d_in[1];
    const int*   pairs   = (const int*)d_in[2];
    const float* node_w1 = (const float*)d_in[3];
    const float* node_b1 = (const float*)d_in[4];
    const float* node_w2 = (const float*)d_in[5];
    const float* node_b2 = (const float*)d_in[6];
    const float* pm_w1   = (const float*)d_in[7];
    const float* pm_b1   = (const float*)d_in[8];
    const float* pm_w2   = (const float*)d_in[9];
    const float* pm_b2   = (const float*)d_in[10];
    const float* ph_w1   = (const float*)d_in[11];
    const float* ph_b1   = (const float*)d_in[12];
    const float* ph_w2   = (const float*)d_in[13];
    const float* ph_b2   = (const float*)d_in[14];
    const float* ln_g    = (const float*)d_in[15];
    const float* ln_b    = (const float*)d_in[16];
    const float* eh_w1   = (const float*)d_in[17];
    const float* eh_b1   = (const float*)d_in[18];
    const float* eh_w2   = (const float*)d_in[19];
    const float* eh_b2   = (const float*)d_in[20];

    const int N = in_sizes[0] / 3;
    const int E = in_sizes[1] / 2;
    const int P = in_sizes[2] / 2;
    const int* src = eidx;
    const int* dst = eidx + E;

    char* ws = (char*)d_ws;
    size_t off = 0;
    auto alloc = [&](size_t bytes) -> char* {
        char* p = ws + off;
        off += (bytes + 255) & ~(size_t)255;
        return p;
    };
    unsigned short* W1abT = (unsigned short*)alloc((size_t)3 * 256 * 128 * 2);
    unsigned short* PB1T  = (unsigned short*)alloc((size_t)3 * 128 * 256 * 2);
    unsigned short* PH2T  = (unsigned short*)alloc((size_t)3 * 128 * 128 * 2);
    unsigned short* EHT   = (unsigned short*)alloc((size_t)256 * 128 * 2);
    float*          cvec  = (float*)alloc((size_t)3 * 128 * 4);
    unsigned short* Ttab  = (unsigned short*)alloc((size_t)3 * (TGRID + 1) * 128 * 2);
    float*          h     = (float*)alloc((size_t)N * DH * 4);
    unsigned short* hbf   = (unsigned short*)alloc((size_t)N * DH * 2);
    unsigned short* Hsb   = (unsigned short*)alloc((size_t)N * DH * 2);
    unsigned short* Hdb   = (unsigned short*)alloc((size_t)N * DH * 2);
    float*          Hs    = (float*)alloc((size_t)N * DH * 4);
    float*          Hd    = (float*)alloc((size_t)N * DH * 4);
    unsigned int*   Sbf   = (unsigned int*)alloc((size_t)N * 64 * 4);
    int*            epack = (int*)alloc((size_t)(E + 32) * 4);
    int*            cnt   = (int*)alloc((size_t)N * 4);
    int*            rs    = (int*)alloc((size_t)(N + 1) * 4);
    int*            cursor= (int*)alloc((size_t)N * 4);
    float*          cntf  = (float*)alloc((size_t)N * 4);
    (void)ws_size; (void)n_in; (void)out_size;

    hipError_t _e = hipMemsetAsync(cnt, 0, (size_t)N * 4, stream); (void)_e;

    const int PREP_TOT = 3 * 256 * 128 + 256 * 128 + 3 * 128 * 256 + 3 * 128 * 128
                       + 3 * 128 + 3 * (TGRID + 1) * 128;
    const int PB = (PREP_TOT + 255) / 256;
    const int NODEB = (N + 31) / 32;
    const int CNTB = (E + 255) / 256;
    prep_all_kernel<<<PB + NODEB + CNTB, 256, 0, stream>>>(pm_w1, eh_w1, ph_w1, ph_w2,
                                                           pm_w2, pm_b2,
                                                           W1abT, EHT, PB1T, PH2T,
                                                           cvec, Ttab, cnt, dst, E,
                                                           xyr, node_w1, node_b1, node_w2, node_b2,
                                                           h, hbf, N, PB, NODEB);

    scan_kernel<<<1, 1024, 0, stream>>>(cnt, rs, cursor, cntf, N);
    fill_kernel<<<(E + 255) / 256, 256, 0, stream>>>(src, dst, cursor, xyr, epack, E);

    const int MB  = (N + 63) / 64;
    const int MB2 = (N + 31) / 32;
    proj_kernel<<<MB, 256, 0, stream>>>(hbf, W1abT, Hsb, Hdb, N);
    for (int l = 0; l < 3; ++l) {
        edge_kernel<<<N, 64, 0, stream>>>(Hsb, Hdb, Ttab + (size_t)l * (TGRID + 1) * 128,
                                          pm_b1 + l * DH, rs, epack, Sbf, N);
        if (l < 2) {
            upd_kernel<0><<<MB2, 256, 0, stream>>>(hbf, (const unsigned short*)Sbf, h,
                                                   PB1T + (size_t)l * 128 * 256, ph_b1 + l * DH,
                                                   cvec + l * 128, cntf,
                                                   PH2T + (size_t)l * 128 * 128, ph_b2 + l * DH,
                                                   ln_g + l * DH, ln_b + l * DH,
                                                   W1abT + (size_t)(l + 1) * 256 * 128,
                                                   Hsb, Hdb, nullptr, nullptr, N);
        } else {
            upd_kernel<1><<<MB2, 256, 0, stream>>>(hbf, (const unsigned short*)Sbf, h,
                                                   PB1T + (size_t)l * 128 * 256, ph_b1 + l * DH,
                                                   cvec + l * 128, cntf,
                                                   PH2T + (size_t)l * 128 * 128, ph_b2 + l * DH,
                                                   ln_g + l * DH, ln_b + l * DH,
                                                   EHT, nullptr, nullptr, Hs, Hd, N);
        }
    }

    pair_kernel<<<(P + 15) / 16, 256, 0, stream>>>(Hs, Hd, pairs, xyr, eh_w1 + 256 * DH,
                                                   eh_b1, eh_w2, eh_b2, (float*)d_out, P);
}

// Round 18
// 326.770 us; speedup vs baseline: 1.0495x; 1.0028x over previous
//
#include <hip/hip_runtime.h>

#define DH 128
#define RMAXF 1.41421356237309515f
#define TGRID 2048

typedef float  floatx4 __attribute__((ext_vector_type(4)));
typedef float  floatx2 __attribute__((ext_vector_type(2)));
typedef short  shortx8 __attribute__((ext_vector_type(8)));
typedef int    intx4  __attribute__((ext_vector_type(4)));

__device__ __forceinline__ unsigned short f2bf(float f) {
    unsigned u = __builtin_bit_cast(unsigned, f);
    u += 0x7fffu + ((u >> 16) & 1u);
    return (unsigned short)(u >> 16);
}
__device__ __forceinline__ floatx2 unpack_bf2(unsigned u) {
    floatx2 r;
    r.x = __builtin_bit_cast(float, u << 16);
    r.y = __builtin_bit_cast(float, u & 0xffff0000u);
    return r;
}
__device__ __forceinline__ float fast_silu(float x) {
    return x * __builtin_amdgcn_rcpf(1.f + __expf(-x));
}

// ---- one prep kernel: bf16 transposed weights, W2P via wave-per-row coalesced dots,
//      bf16 NN RBF table, node-encoder tail blocks, degree-count tail blocks ----
__global__ __launch_bounds__(256)
void prep_all_kernel(const float* __restrict__ pm_w1, const float* __restrict__ eh_w1,
                     const float* __restrict__ ph_w1, const float* __restrict__ ph_w2,
                     const float* __restrict__ pm_w2, const float* __restrict__ pm_b2,
                     unsigned short* __restrict__ W1abT, unsigned short* __restrict__ EHT,
                     unsigned short* __restrict__ PB1T, unsigned short* __restrict__ PH2T,
                     float* __restrict__ cvec, unsigned short* __restrict__ Tb,
                     int* __restrict__ cnt, const int* __restrict__ dst, int E,
                     const float* __restrict__ xyr,
                     const float* __restrict__ nw1, const float* __restrict__ nb1,
                     const float* __restrict__ nw2, const float* __restrict__ nb2,
                     float* __restrict__ h, unsigned short* __restrict__ hbf,
                     int N, int PB, int NODEB) {
    if ((int)blockIdx.x >= PB + NODEB) {
        int e = ((int)blockIdx.x - PB - NODEB) * 256 + threadIdx.x;
        if (e < E) atomicAdd(&cnt[dst[e]], 1);
        return;
    }
    if ((int)blockIdx.x >= PB) {
        __shared__ float xs[32][3];
        __shared__ float hid[32][DH];
        const int g = threadIdx.x >> 7;
        const int t = threadIdx.x & 127;
        const int n0 = ((int)blockIdx.x - PB) * 32 + g * 16;
        if (t < 48) {
            int i = t / 3, j = t - 3 * (t / 3);
            int n = n0 + i; if (n >= N) n = N - 1;
            xs[g * 16 + i][j] = xyr[3 * n + j];
        }
        __syncthreads();
        int col = t;
        float w10 = nw1[col], w11 = nw1[DH + col], w12 = nw1[2 * DH + col];
        float bb = nb1[col];
#pragma unroll
        for (int i = 0; i < 16; ++i) {
            float v = bb + xs[g * 16 + i][0] * w10 + xs[g * 16 + i][1] * w11 + xs[g * 16 + i][2] * w12;
            hid[g * 16 + i][col] = fast_silu(v);
        }
        __syncthreads();
        float a[16];
#pragma unroll
        for (int i = 0; i < 16; ++i) a[i] = nb2[col];
        for (int j = 0; j < DH; ++j) {
            float wv = nw2[j * DH + col];
#pragma unroll
            for (int i = 0; i < 16; ++i) a[i] += hid[g * 16 + i][j] * wv;
        }
        for (int i = 0; i < 16; ++i) {
            int n = n0 + i;
            if (n < N) {
                h[(size_t)n * DH + col] = a[i];
                hbf[(size_t)n * DH + col] = f2bf(a[i]);
            }
        }
        return;
    }
    int idx = blockIdx.x * 256 + threadIdx.x;
    const int nA = 3 * 256 * 128;
    const int nB = 256 * 128;
    const int nC = 3 * 128 * 256;
    const int nD = 3 * 128 * 128;
    const int nE = 3 * 128;
    const int nT = 3 * (TGRID + 1) * 128;
    const int nW = 3 * 128 * 64;        // 384 waves: one per W2P output row
    if (idx < nA) {
        int l = idx / (256 * 128);
        int rem = idx - l * 256 * 128;
        int j = rem >> 7, k = rem & 127;
        int srow = ((j >> 7) << 7) + k;
        W1abT[idx] = f2bf(pm_w1[(size_t)l * 272 * 128 + (size_t)srow * 128 + (j & 127)]);
        return;
    }
    idx -= nA;
    if (idx < nB) {
        int j = idx >> 7, k = idx & 127;
        int srow = ((j >> 7) << 7) + k;
        EHT[idx] = f2bf(eh_w1[(size_t)srow * 128 + (j & 127)]);
        return;
    }
    idx -= nB;
    if (idx < nC) {
        int l = idx / (128 * 256);
        int rem = idx - l * 128 * 256;
        int j = rem >> 8, k = rem & 255;
        if (k < 128) {
            PB1T[idx] = f2bf(ph_w1[(size_t)l * 256 * 128 + (size_t)k * 128 + j]);
        }
        // k >= 128 handled by the nW wave-per-row region below
        return;
    }
    idx -= nC;
    if (idx < nD) {
        int l = idx / (128 * 128);
        int rem = idx - l * 128 * 128;
        int j = rem >> 7, k = rem & 127;
        PH2T[idx] = f2bf(ph_w2[(size_t)l * 128 * 128 + (size_t)k * 128 + j]);
        return;
    }
    idx -= nD;
    if (idx < nE) {
        int l = idx >> 7, o = idx & 127;
        const float* b2 = pm_b2 + l * 128;
        const float* p1b = ph_w1 + (size_t)l * 256 * 128 + (size_t)128 * 128 + o;
        float s = 0.f;
        for (int m = 0; m < 128; ++m) s += b2[m] * p1b[(size_t)m * 128];
        cvec[idx] = s;
        return;
    }
    idx -= nE;
    if (idx < nT) {
        int l = idx / ((TGRID + 1) * 128);
        int rem = idx - l * (TGRID + 1) * 128;
        int i = rem >> 7, ch = rem & 127;
        float r = (float)i * (RMAXF / (float)TGRID);
        const float step = RMAXF / 15.f;
        const float gamma = 56.25f;
        const float* w1c = pm_w1 + (size_t)l * 272 * 128 + (size_t)256 * 128 + ch;
        float s = 0.f;
#pragma unroll
        for (int k = 0; k < 16; ++k) {
            float d = r - (float)k * step;
            s += expf(-gamma * d * d) * w1c[(size_t)k * 128];
        }
        Tb[idx] = f2bf(s);
        return;
    }
    idx -= nT;
    if (idx < nW) {
        // W2P[l][kk][j] = sum_m pm_w2[l][kk][m] * ph_w1[l][128+m][j]
        // one wave per (l,kk); lanes own j pairs -> coalesced p1b loads, broadcast w2r
        int wid = idx >> 6;
        int lane = idx & 63;
        int l = wid >> 7;
        int kk = wid & 127;
        const float* w2r = pm_w2 + (size_t)l * 128 * 128 + (size_t)kk * 128;
        const float* p1b = ph_w1 + (size_t)l * 256 * 128 + (size_t)128 * 128;
        int j0 = lane * 2;
        float s0 = 0.f, s1 = 0.f;
        for (int m = 0; m < 128; ++m) {
            float wv = w2r[m];
            s0 += wv * p1b[(size_t)m * 128 + j0];
            s1 += wv * p1b[(size_t)m * 128 + j0 + 1];
        }
        unsigned short* o = PB1T + (size_t)l * 128 * 256 + 128 + kk;
        o[(size_t)j0 * 256] = f2bf(s0);
        o[(size_t)(j0 + 1) * 256] = f2bf(s1);
    }
}

// ---- CSR scan ----
__global__ __launch_bounds__(1024)
void scan_kernel(const int* __restrict__ cnt, int* __restrict__ rs, int* __restrict__ cursor,
                 float* __restrict__ cntf, int N) {
    __shared__ int ps[1024];
    const int CH = 16;
    int t = threadIdx.x;
    int base = t * CH;
    int loc[CH];
    int s = 0;
#pragma unroll
    for (int j = 0; j < CH; ++j) {
        int i = base + j;
        int v = (i < N) ? cnt[i] : 0;
        if (i < N) cntf[i] = (float)v;
        loc[j] = s; s += v;
    }
    ps[t] = s;
    __syncthreads();
    for (int off = 1; off < 1024; off <<= 1) {
        int v = (t >= off) ? ps[t - off] : 0;
        __syncthreads();
        ps[t] += v;
        __syncthreads();
    }
    int pre = (t > 0) ? ps[t - 1] : 0;
#pragma unroll
    for (int j = 0; j < CH; ++j) {
        int i = base + j;
        if (i < N) { int v = pre + loc[j]; rs[i] = v; cursor[i] = v; }
    }
    if (t == 0) rs[N] = ps[1023];
}
// ---- fill: per CSR slot store packed {src | T-row-index<<18}; pads 32 tail slots ----
__global__ void fill_kernel(const int* __restrict__ src, const int* __restrict__ dst,
                            int* __restrict__ cursor, const float* __restrict__ xyr,
                            int* __restrict__ epack, int E) {
    int e = blockIdx.x * 256 + threadIdx.x;
    if (e < 32) epack[E + e] = 0;
    if (e >= E) return;
    int s = src[e], d = dst[e];
    int p = atomicAdd(&cursor[d], 1);
    float dx = xyr[3 * s] - xyr[3 * d];
    float dy = xyr[3 * s + 1] - xyr[3 * d + 1];
    float r = sqrtf(dx * dx + dy * dy + 1e-8f);
    int ti = (int)(r * ((float)TGRID / RMAXF) + 0.5f);
    ti = (ti > TGRID) ? TGRID : ti;
    epack[p] = s | (ti << 18);
}

// ---- proj (layer-0): Hsb||Hdb (bf16) = hbf @ W1abT^T ----
__global__ __launch_bounds__(256)
void proj_kernel(const unsigned short* __restrict__ Abf,
                 const unsigned short* __restrict__ BT,
                 unsigned short* __restrict__ O1b, unsigned short* __restrict__ O2b, int M) {
    const int tid = threadIdx.x;
    const int w = tid >> 6, lane = tid & 63;
    const int mr = lane & 15, q = lane >> 4;
    const int row0 = blockIdx.x * 64;
    floatx4 acc[4][4] = {};
#pragma unroll
    for (int kc = 0; kc < 4; ++kc) {
        const int ko = kc * 32 + q * 8;
        shortx8 a[4], b[4];
#pragma unroll
        for (int mt = 0; mt < 4; ++mt) {
            int r = row0 + mt * 16 + mr; if (r >= M) r = M - 1;
            a[mt] = *reinterpret_cast<const shortx8*>(Abf + (size_t)r * DH + ko);
        }
#pragma unroll
        for (int nt = 0; nt < 4; ++nt) {
            int ocol = w * 64 + nt * 16 + mr;
            b[nt] = *reinterpret_cast<const shortx8*>(BT + (size_t)ocol * DH + ko);
        }
#pragma unroll
        for (int mt = 0; mt < 4; ++mt)
#pragma unroll
            for (int nt = 0; nt < 4; ++nt)
                acc[mt][nt] = __builtin_amdgcn_mfma_f32_16x16x32_bf16(a[mt], b[nt], acc[mt][nt], 0, 0, 0);
    }
#pragma unroll
    for (int nt = 0; nt < 4; ++nt) {
        int ocol = w * 64 + nt * 16 + mr;
        unsigned short* O = (ocol < DH) ? O1b : O2b;
        int col = ocol & (DH - 1);
#pragma unroll
        for (int mt = 0; mt < 4; ++mt)
#pragma unroll
            for (int r4 = 0; r4 < 4; ++r4) {
                int gr = row0 + mt * 16 + q * 4 + r4;
                if (gr < M) O[(size_t)gr * DH + col] = f2bf(acc[mt][nt][r4]);
            }
    }
}

// ---- edge stream + aggregate: ONE WAVE = ONE NODE = ONE BLOCK; batch-4 prefetch,
//      mask hoisted out of hot loop ----
__global__ __launch_bounds__(64)
void edge_kernel(const unsigned short* __restrict__ Hsb, const unsigned short* __restrict__ Hdb,
                 const unsigned short* __restrict__ Tb,
                 const float* __restrict__ b1,
                 const int* __restrict__ rs, const int* __restrict__ epack,
                 unsigned int* __restrict__ Sbf, int N) {
    const int n = blockIdx.x;
    const int lane = threadIdx.x;
    const int c = lane * 2;
    floatx2 hdn = unpack_bf2(*(const unsigned*)(Hdb + (size_t)n * DH + c))
                + *(const floatx2*)(b1 + c);
    const int s = rs[n], e = rs[n + 1];
    floatx2 acc = {0.f, 0.f};
    const int cnt = e - s;
    if (cnt > 0) {
        const int nb = (cnt + 3) >> 2;
        intx4 pk = __builtin_nontemporal_load((const intx4*)(epack + s));
        unsigned hu[4], tw[4];
        {
            int p0 = pk.x, p1 = pk.y, p2 = pk.z, p3 = pk.w;
            hu[0] = *(const unsigned*)(Hsb + (size_t)(p0 & 0x3ffff) * DH + c);
            hu[1] = *(const unsigned*)(Hsb + (size_t)(p1 & 0x3ffff) * DH + c);
            hu[2] = *(const unsigned*)(Hsb + (size_t)(p2 & 0x3ffff) * DH + c);
            hu[3] = *(const unsigned*)(Hsb + (size_t)(p3 & 0x3ffff) * DH + c);
            tw[0] = *(const unsigned*)(Tb + (size_t)(((unsigned)p0) >> 18) * DH + c);
            tw[1] = *(const unsigned*)(Tb + (size_t)(((unsigned)p1) >> 18) * DH + c);
            tw[2] = *(const unsigned*)(Tb + (size_t)(((unsigned)p2) >> 18) * DH + c);
            tw[3] = *(const unsigned*)(Tb + (size_t)(((unsigned)p3) >> 18) * DH + c);
        }
        for (int b = 0; b < nb - 1; ++b) {
            const int j = s + b * 4;
            intx4 pkN = __builtin_nontemporal_load((const intx4*)(epack + j + 4));
            unsigned huN[4], twN[4];
            {
                int p0 = pkN.x, p1 = pkN.y, p2 = pkN.z, p3 = pkN.w;
                huN[0] = *(const unsigned*)(Hsb + (size_t)(p0 & 0x3ffff) * DH + c);
                huN[1] = *(const unsigned*)(Hsb + (size_t)(p1 & 0x3ffff) * DH + c);
                huN[2] = *(const unsigned*)(Hsb + (size_t)(p2 & 0x3ffff) * DH + c);
                huN[3] = *(const unsigned*)(Hsb + (size_t)(p3 & 0x3ffff) * DH + c);
                twN[0] = *(const unsigned*)(Tb + (size_t)(((unsigned)p0) >> 18) * DH + c);
                twN[1] = *(const unsigned*)(Tb + (size_t)(((unsigned)p1) >> 18) * DH + c);
                twN[2] = *(const unsigned*)(Tb + (size_t)(((unsigned)p2) >> 18) * DH + c);
                twN[3] = *(const unsigned*)(Tb + (size_t)(((unsigned)p3) >> 18) * DH + c);
            }
#pragma unroll
            for (int i = 0; i < 4; ++i) {
                floatx2 pre = unpack_bf2(hu[i]) + hdn + unpack_bf2(tw[i]);
                floatx2 sg;
                sg.x = __builtin_amdgcn_rcpf(1.f + __expf(-pre.x));
                sg.y = __builtin_amdgcn_rcpf(1.f + __expf(-pre.y));
                acc += pre * sg;
            }
#pragma unroll
            for (int i = 0; i < 4; ++i) { hu[i] = huN[i]; tw[i] = twN[i]; }
        }
        {
            const int j = s + (nb - 1) * 4;
#pragma unroll
            for (int i = 0; i < 4; ++i) {
                floatx2 pre = unpack_bf2(hu[i]) + hdn + unpack_bf2(tw[i]);
                floatx2 sg;
                sg.x = __builtin_amdgcn_rcpf(1.f + __expf(-pre.x));
                sg.y = __builtin_amdgcn_rcpf(1.f + __expf(-pre.y));
                float msk = (j + i < e) ? 1.f : 0.f;
                acc += (pre * sg) * msk;
            }
        }
    }
    unsigned lo = f2bf(acc.x), hi = f2bf(acc.y);
    Sbf[(size_t)n * 64 + lane] = lo | (hi << 16);
}

// ---- node update + fused next-layer projection; 32-row tiles ----
template<int LAST>
__global__ __launch_bounds__(256)
void upd_kernel(unsigned short* hbf,
                const unsigned short* __restrict__ Sbf16,
                float* h,
                const unsigned short* __restrict__ PB1T,
                const float* __restrict__ b1v,
                const float* __restrict__ cvec,
                const float* __restrict__ cntf,
                const unsigned short* __restrict__ P2T,
                const float* __restrict__ b2v,
                const float* __restrict__ g, const float* __restrict__ bb,
                const unsigned short* __restrict__ BT,
                unsigned short* __restrict__ O1b, unsigned short* __restrict__ O2b,
                float* __restrict__ O1f, float* __restrict__ O2f,
                int M) {
    __shared__ unsigned short HID[32 * 136];
    __shared__ float red[4][32][2];
    __shared__ float stats[32][2];
    __shared__ float cntL[32];
    const int tid = threadIdx.x;
    const int w = tid >> 6, lane = tid & 63;
    const int mr = lane & 15, q = lane >> 4;
    const int row0 = blockIdx.x * 32;

    if (tid < 32) {
        int r = row0 + tid;
        cntL[tid] = (r < M) ? cntf[r] : 0.f;
    }
    __syncthreads();

    floatx4 acc[2][2] = {};
#pragma unroll
    for (int kc = 0; kc < 8; ++kc) {
        const int ko = kc * 32 + q * 8;
        shortx8 a[2], bfr[2];
#pragma unroll
        for (int mt = 0; mt < 2; ++mt) {
            int r = row0 + mt * 16 + mr; if (r >= M) r = M - 1;
            const unsigned short* sp = (ko < DH) ? (hbf + (size_t)r * DH + ko)
                                                 : (Sbf16 + (size_t)r * DH + (ko - DH));
            a[mt] = *reinterpret_cast<const shortx8*>(sp);
        }
#pragma unroll
        for (int nt = 0; nt < 2; ++nt)
            bfr[nt] = *reinterpret_cast<const shortx8*>(PB1T + (size_t)(w * 32 + nt * 16 + mr) * 256 + ko);
#pragma unroll
        for (int mt = 0; mt < 2; ++mt)
#pragma unroll
            for (int nt = 0; nt < 2; ++nt)
                acc[mt][nt] = __builtin_amdgcn_mfma_f32_16x16x32_bf16(a[mt], bfr[nt], acc[mt][nt], 0, 0, 0);
    }
#pragma unroll
    for (int nt = 0; nt < 2; ++nt) {
        int col = w * 32 + nt * 16 + mr;
        float bv = b1v[col], cv = cvec[col];
#pragma unroll
        for (int mt = 0; mt < 2; ++mt)
#pragma unroll
            for (int r4 = 0; r4 < 4; ++r4) {
                int row = mt * 16 + q * 4 + r4;
                HID[row * 136 + col] = f2bf(fast_silu(acc[mt][nt][r4] + bv + cntL[row] * cv));
            }
    }
    __syncthreads();

    floatx4 acc3[2][2] = {};
#pragma unroll
    for (int kc = 0; kc < 4; ++kc) {
        const int ko = kc * 32 + q * 8;
        shortx8 a[2], bfr[2];
#pragma unroll
        for (int mt = 0; mt < 2; ++mt)
            a[mt] = *reinterpret_cast<const shortx8*>(HID + (mt * 16 + mr) * 136 + ko);
#pragma unroll
        for (int nt = 0; nt < 2; ++nt)
            bfr[nt] = *reinterpret_cast<const shortx8*>(P2T + (size_t)(w * 32 + nt * 16 + mr) * DH + ko);
#pragma unroll
        for (int mt = 0; mt < 2; ++mt)
#pragma unroll
            for (int nt = 0; nt < 2; ++nt)
                acc3[mt][nt] = __builtin_amdgcn_mfma_f32_16x16x32_bf16(a[mt], bfr[nt], acc3[mt][nt], 0, 0, 0);
    }
#pragma unroll
    for (int nt = 0; nt < 2; ++nt) {
        int col = w * 32 + nt * 16 + mr;
        float b2c = b2v[col];
#pragma unroll
        for (int mt = 0; mt < 2; ++mt)
#pragma unroll
            for (int r4 = 0; r4 < 4; ++r4) {
                int gr = row0 + mt * 16 + q * 4 + r4;
                float hv = (gr < M) ? h[(size_t)gr * DH + col] : 0.f;
                acc3[mt][nt][r4] = acc3[mt][nt][r4] + b2c + hv;
            }
    }
#pragma unroll
    for (int mt = 0; mt < 2; ++mt)
#pragma unroll
        for (int r4 = 0; r4 < 4; ++r4) {
            float y0 = acc3[mt][0][r4], y1 = acc3[mt][1][r4];
            float s1 = y0 + y1, s2 = y0 * y0 + y1 * y1;
#pragma unroll
            for (int m = 1; m < 16; m <<= 1) {
                s1 += __shfl_xor(s1, m);
                s2 += __shfl_xor(s2, m);
            }
            if (mr == 0) {
                int row = mt * 16 + q * 4 + r4;
                red[w][row][0] = s1; red[w][row][1] = s2;
            }
        }
    __syncthreads();
    if (tid < 32) {
        float s1 = red[0][tid][0] + red[1][tid][0] + red[2][tid][0] + red[3][tid][0];
        float s2 = red[0][tid][1] + red[1][tid][1] + red[2][tid][1] + red[3][tid][1];
        float mu = s1 * (1.f / DH);
        float var = s2 * (1.f / DH) - mu * mu;
        stats[tid][0] = mu;
        stats[tid][1] = rsqrtf(var + 1e-5f);
    }
    __syncthreads();
#pragma unroll
    for (int nt = 0; nt < 2; ++nt) {
        int col = w * 32 + nt * 16 + mr;
        float gc = g[col], bc = bb[col];
#pragma unroll
        for (int mt = 0; mt < 2; ++mt)
#pragma unroll
            for (int r4 = 0; r4 < 4; ++r4) {
                int row = mt * 16 + q * 4 + r4;
                int gr = row0 + row;
                if (gr < M) {
                    float yv = (acc3[mt][nt][r4] - stats[row][0]) * stats[row][1] * gc + bc;
                    unsigned short yb = f2bf(yv);
                    h[(size_t)gr * DH + col] = yv;
                    hbf[(size_t)gr * DH + col] = yb;
                    HID[row * 136 + col] = yb;
                }
            }
    }
    __syncthreads();

    floatx4 acc4[2][4] = {};
#pragma unroll
    for (int kc = 0; kc < 4; ++kc) {
        const int ko = kc * 32 + q * 8;
        shortx8 a[2], b[4];
#pragma unroll
        for (int mt = 0; mt < 2; ++mt)
            a[mt] = *reinterpret_cast<const shortx8*>(HID + (mt * 16 + mr) * 136 + ko);
#pragma unroll
        for (int nt = 0; nt < 4; ++nt) {
            int ocol = w * 64 + nt * 16 + mr;
            b[nt] = *reinterpret_cast<const shortx8*>(BT + (size_t)ocol * DH + ko);
        }
#pragma unroll
        for (int mt = 0; mt < 2; ++mt)
#pragma unroll
            for (int nt = 0; nt < 4; ++nt)
                acc4[mt][nt] = __builtin_amdgcn_mfma_f32_16x16x32_bf16(a[mt], b[nt], acc4[mt][nt], 0, 0, 0);
    }
#pragma unroll
    for (int nt = 0; nt < 4; ++nt) {
        int ocol = w * 64 + nt * 16 + mr;
        int col = ocol & (DH - 1);
#pragma unroll
        for (int mt = 0; mt < 2; ++mt)
#pragma unroll
            for (int r4 = 0; r4 < 4; ++r4) {
                int gr = row0 + mt * 16 + q * 4 + r4;
                if (gr < M) {
                    if (LAST) {
                        float* O = (ocol < DH) ? O1f : O2f;
                        O[(size_t)gr * DH + col] = acc4[mt][nt][r4];
                    } else {
                        unsigned short* O = (ocol < DH) ? O1b : O2b;
                        O[(size_t)gr * DH + col] = f2bf(acc4[mt][nt][r4]);
                    }
                }
            }
    }
}

// ---- pair head: 4 pairs per wave (16-lane groups, 8 channels/lane via 2x float4) ----
__global__ __launch_bounds__(256)
void pair_kernel(const float* __restrict__ Hu, const float* __restrict__ Hv,
                 const int* __restrict__ pairs, const float* __restrict__ xyr,
                 const float* __restrict__ ehw1c,
                 const float* __restrict__ eb1, const float* __restrict__ ew2,
                 const float* __restrict__ eb2,
                 float* __restrict__ out, int P) {
    int grp = threadIdx.x >> 4;
    int p = blockIdx.x * 16 + grp;
    bool valid = (p < P);
    int pp = valid ? p : (P - 1);
    int u = pairs[2 * pp], v = pairs[2 * pp + 1];
    float ru = xyr[3 * u + 2], rv_ = xyr[3 * v + 2];
    float dx = xyr[3 * u] - xyr[3 * v];
    float dy = xyr[3 * u + 1] - xyr[3 * v + 1];
    float dist = sqrtf(dx * dx + dy * dy + 1e-8f);
    float adr = fabsf(ru - rv_);
    int c = (threadIdx.x & 15) * 8;
    float val = 0.f;
#pragma unroll
    for (int hf = 0; hf < 2; ++hf) {
        int cc = c + hf * 4;
        floatx4 hu4 = *(const floatx4*)(Hu + (size_t)u * DH + cc);
        floatx4 hv4 = *(const floatx4*)(Hv + (size_t)v * DH + cc);
        floatx4 bv = *(const floatx4*)(eb1 + cc);
        floatx4 wv = *(const floatx4*)(ew2 + cc);
        floatx4 c0 = *(const floatx4*)(ehw1c + 0 * DH + cc);
        floatx4 c1 = *(const floatx4*)(ehw1c + 1 * DH + cc);
        floatx4 c2 = *(const floatx4*)(ehw1c + 2 * DH + cc);
        floatx4 c3 = *(const floatx4*)(ehw1c + 3 * DH + cc);
        floatx4 px = hu4 + hv4 + bv + ru * c0 + rv_ * c1 + dist * c2 + adr * c3;
        val += fast_silu(px.x) * wv.x + fast_silu(px.y) * wv.y +
               fast_silu(px.z) * wv.z + fast_silu(px.w) * wv.w;
    }
#pragma unroll
    for (int m = 1; m < 16; m <<= 1) val += __shfl_xor(val, m);
    if (((threadIdx.x & 15) == 0) && valid) out[p] = val + eb2[0];
}

extern "C" void kernel_launch(void* const* d_in, const int* in_sizes, int n_in,
                              void* d_out, int out_size, void* d_ws, size_t ws_size,
                              hipStream_t stream) {
    const float* xyr     = (const float*)d_in[0];
    const int*   eidx    = (const int*)d_in[1];
    const int*   pairs   = (const int*)d_in[2];
    const float* node_w1 = (const float*)d_in[3];
    const float* node_b1 = (const float*)d_in[4];
    const float* node_w2 = (const float*)d_in[5];
    const float* node_b2 = (const float*)d_in[6];
    const float* pm_w1   = (const float*)d_in[7];
    const float* pm_b1   = (const float*)d_in[8];
    const float* pm_w2   = (const float*)d_in[9];
    const float* pm_b2   = (const float*)d_in[10];
    const float* ph_w1   = (const float*)d_in[11];
    const float* ph_b1   = (const float*)d_in[12];
    const float* ph_w2   = (const float*)d_in[13];
    const float* ph_b2   = (const float*)d_in[14];
    const float* ln_g    = (const float*)d_in[15];
    const float* ln_b    = (const float*)d_in[16];
    const float* eh_w1   = (const float*)d_in[17];
    const float* eh_b1   = (const float*)d_in[18];
    const float* eh_w2   = (const float*)d_in[19];
    const float* eh_b2   = (const float*)d_in[20];

    const int N = in_sizes[0] / 3;
    const int E = in_sizes[1] / 2;
    const int P = in_sizes[2] / 2;
    const int* src = eidx;
    const int* dst = eidx + E;

    char* ws = (char*)d_ws;
    size_t off = 0;
    auto alloc = [&](size_t bytes) -> char* {
        char* p = ws + off;
        off += (bytes + 255) & ~(size_t)255;
        return p;
    };
    unsigned short* W1abT = (unsigned short*)alloc((size_t)3 * 256 * 128 * 2);
    unsigned short* PB1T  = (unsigned short*)alloc((size_t)3 * 128 * 256 * 2);
    unsigned short* PH2T  = (unsigned short*)alloc((size_t)3 * 128 * 128 * 2);
    unsigned short* EHT   = (unsigned short*)alloc((size_t)256 * 128 * 2);
    float*          cvec  = (float*)alloc((size_t)3 * 128 * 4);
    unsigned short* Ttab  = (unsigned short*)alloc((size_t)3 * (TGRID + 1) * 128 * 2);
    float*          h     = (float*)alloc((size_t)N * DH * 4);
    unsigned short* hbf   = (unsigned short*)alloc((size_t)N * DH * 2);
    unsigned short* Hsb   = (unsigned short*)alloc((size_t)N * DH * 2);
    unsigned short* Hdb   = (unsigned short*)alloc((size_t)N * DH * 2);
    float*          Hs    = (float*)alloc((size_t)N * DH * 4);
    float*          Hd    = (float*)alloc((size_t)N * DH * 4);
    unsigned int*   Sbf   = (unsigned int*)alloc((size_t)N * 64 * 4);
    int*            epack = (int*)alloc((size_t)(E + 32) * 4);
    int*            cnt   = (int*)alloc((size_t)N * 4);
    int*            rs    = (int*)alloc((size_t)(N + 1) * 4);
    int*            cursor= (int*)alloc((size_t)N * 4);
    float*          cntf  = (float*)alloc((size_t)N * 4);
    (void)ws_size; (void)n_in; (void)out_size;

    hipError_t _e = hipMemsetAsync(cnt, 0, (size_t)N * 4, stream); (void)_e;

    const int PREP_TOT = 3 * 256 * 128 + 256 * 128 + 3 * 128 * 256 + 3 * 128 * 128
                       + 3 * 128 + 3 * (TGRID + 1) * 128 + 3 * 128 * 64;
    const int PB = (PREP_TOT + 255) / 256;
    const int NODEB = (N + 31) / 32;
    const int CNTB = (E + 255) / 256;
    prep_all_kernel<<<PB + NODEB + CNTB, 256, 0, stream>>>(pm_w1, eh_w1, ph_w1, ph_w2,
                                                           pm_w2, pm_b2,
                                                           W1abT, EHT, PB1T, PH2T,
                                                           cvec, Ttab, cnt, dst, E,
                                                           xyr, node_w1, node_b1, node_w2, node_b2,
                                                           h, hbf, N, PB, NODEB);

    scan_kernel<<<1, 1024, 0, stream>>>(cnt, rs, cursor, cntf, N);
    fill_kernel<<<(E + 255) / 256, 256, 0, stream>>>(src, dst, cursor, xyr, epack, E);

    const int MB  = (N + 63) / 64;
    const int MB2 = (N + 31) / 32;
    proj_kernel<<<MB, 256, 0, stream>>>(hbf, W1abT, Hsb, Hdb, N);
    for (int l = 0; l < 3; ++l) {
        edge_kernel<<<N, 64, 0, stream>>>(Hsb, Hdb, Ttab + (size_t)l * (TGRID + 1) * 128,
                                          pm_b1 + l * DH, rs, epack, Sbf, N);
        if (l < 2) {
            upd_kernel<0><<<MB2, 256, 0, stream>>>(hbf, (const unsigned short*)Sbf, h,
                                                   PB1T + (size_t)l * 128 * 256, ph_b1 + l * DH,
                                                   cvec + l * 128, cntf,
                                                   PH2T + (size_t)l * 128 * 128, ph_b2 + l * DH,
                                                   ln_g + l * DH, ln_b + l * DH,
                                                   W1abT + (size_t)(l + 1) * 256 * 128,
                                                   Hsb, Hdb, nullptr, nullptr, N);
        } else {
            upd_kernel<1><<<MB2, 256, 0, stream>>>(hbf, (const unsigned short*)Sbf, h,
                                                   PB1T + (size_t)l * 128 * 256, ph_b1 + l * DH,
                                                   cvec + l * 128, cntf,
                                                   PH2T + (size_t)l * 128 * 128, ph_b2 + l * DH,
                                                   ln_g + l * DH, ln_b + l * DH,
                                                   EHT, nullptr, nullptr, Hs, Hd, N);
        }
    }

    pair_kernel<<<(P + 15) / 16, 256, 0, stream>>>(Hs, Hd, pairs, xyr, eh_w1 + 256 * DH,
                                                   eh_b1, eh_w2, eh_b2, (float*)d_out, P);
}